// Round 2
// baseline (19624.316 us; speedup 1.0000x reference)
//
#include <hip/hip_runtime.h>

namespace {

constexpr int Vv=30000, Ll=400, Bb=16, Tt=145;
constexpr int Ee=100, EHh=150, DHh=200, ENc=300;
constexpr int SOS_TOK=1;
constexpr int NB=256, NT=256;

// ---- d_out used as scratch before decoder writes it (time-disjoint) ----
constexpr long SO_EMB = 0;                      // [6400][100]
constexpr long SO_GIF = SO_EMB + 6400L*100;     // [6400][450]
constexpr long SO_GIB = SO_GIF + 6400L*450;     // [6400][450]
constexpr long SO_ENC = SO_GIB + 6400L*450;     // [6400][300]
constexpr long SO_WCAT= SO_GIF;                 // [301][300] staged after encoder (gi dead)

// ---- ws float offsets ----
constexpr long OFF_M    = 0;                    // [6400][200]
constexpr long OFF_N    = OFF_M + 6400L*200;    // [6400][100]
constexpr long OFF_Q    = OFF_N + 6400L*100;    // [6400]
constexpr long OFF_HENC = OFF_Q + 6400;         // [2dir][2par][16][150]
constexpr long OFF_HDEC = OFF_HENC + 4L*Bb*EHh; // [2par][16][200]
constexpr long OFF_COVER= OFF_HDEC + 2L*Bb*DHh; // [16][400]
constexpr long OFF_EXPE = OFF_COVER + 6400;     // [2par][400][16]
constexpr long OFF_PREH = OFF_EXPE + 2L*6400;   // [2par][16][104]
constexpr long OFF_CTXP = OFF_PREH + 2L*16*104; // [2par][16][4][104]
constexpr long OFF_PSUM = OFF_CTXP + 2L*16*4*104; // [256][16]
constexpr long OFF_ZLOG = OFF_PSUM + 4096;      // [2][16]
constexpr long OFF_CAND = OFF_ZLOG + 32;        // [2][16][400][2]
constexpr long WS_F32_END = OFF_CAND + 2L*16*400*2;
constexpr long PMAX_BYTE = ((WS_F32_END*4 + 255)/256)*256;   // u64 [256][16]
constexpr long IWS_BYTE  = PMAX_BYTE + 4096L*8;
constexpr int ISVL=0, IGV=6400, IGLS=12800, ICG0=19216, INGR=23328; // ints, end 23344
constexpr long BAR_BYTE  = ((IWS_BYTE + 23344L*4 + 255)/256)*256;   // 192 ints

struct Args {
  const int* itok;
  const float* emb;
  const float* Wfih; const float* Wfhh; const float* bfih; const float* bfhh;
  const float* Wbih; const float* Wbhh; const float* bbih; const float* bbhh;
  const float* adW; const float* adb;
  const float* dWih; const float* dWhh; const float* dbih; const float* dbhh;
  const float* bilW; const float* bilb; const float* cw;
  const float* ptrW; const float* ptrb;
  const float* preW; const float* preb; const float* outb;
  float* out; float* ws; unsigned long long* pmax; int* iws; int* bar;
};

__device__ __forceinline__ int chunkStart(int c){ return c*117 + (c<48? c:48); }
__device__ __forceinline__ int chunkSize(int c){ return 117 + (c<48?1:0); }
__device__ __forceinline__ float sigm(float x){ return 1.f/(1.f+expf(-x)); }
__device__ __forceinline__ unsigned long long packvi(float val, int v){
  return ((unsigned long long)__float_as_uint(val)<<32) | (unsigned)(~(unsigned)v);
}
#define CTXPV(par,b,g2,k) a.ws[OFF_CTXP+(((long)(par)*16+(b))*4+(g2))*104+(k)]

// ---- device-scope barrier: generation counter, agent fences, abort escape ----
__device__ __forceinline__ void gbar(int* cnt, int* gen, int n, int* abrt){
  __syncthreads();
  if (threadIdx.x==0){
    if (__hip_atomic_load(abrt, __ATOMIC_RELAXED, __HIP_MEMORY_SCOPE_AGENT)==0){
      __builtin_amdgcn_fence(__ATOMIC_RELEASE, "agent");
      int g = __hip_atomic_load(gen, __ATOMIC_RELAXED, __HIP_MEMORY_SCOPE_AGENT);
      int arr = __hip_atomic_fetch_add(cnt, 1, __ATOMIC_RELAXED, __HIP_MEMORY_SCOPE_AGENT);
      if (arr == n-1){
        __hip_atomic_store(cnt, 0, __ATOMIC_RELAXED, __HIP_MEMORY_SCOPE_AGENT);
        __hip_atomic_fetch_add(gen, 1, __ATOMIC_RELEASE, __HIP_MEMORY_SCOPE_AGENT);
      } else {
        long long t0 = clock64();
        while (__hip_atomic_load(gen, __ATOMIC_RELAXED, __HIP_MEMORY_SCOPE_AGENT) == g){
          __builtin_amdgcn_s_sleep(2);
          if (__hip_atomic_load(abrt, __ATOMIC_RELAXED, __HIP_MEMORY_SCOPE_AGENT)!=0) break;
          if (clock64() - t0 > 400000000LL){   // ~0.17s: fail fast, set abort
            __hip_atomic_store(abrt, 1, __ATOMIC_RELAXED, __HIP_MEMORY_SCOPE_AGENT);
            break;
          }
        }
      }
      __builtin_amdgcn_fence(__ATOMIC_ACQUIRE, "agent");
    }
  }
  __syncthreads();
}

// ---- per-b bitonic sort of (tok,l) -> scatter group structures ----
__device__ void sortB(const Args& a, int b, char* smem){
  int tid=threadIdx.x;
  int* key=(int*)smem;  // 513 ints
  key[tid]     = (tid<400)     ? (a.itok[tid*16+b]*400 + tid)           : 0x7FFFFFFF;
  key[tid+256] = ((tid+256)<400)? (a.itok[(tid+256)*16+b]*400 + tid+256): 0x7FFFFFFF;
  __syncthreads();
  for (int k=2;k<=512;k<<=1){
    for (int j=k>>1;j>0;j>>=1){
      int i = (tid/j)*(2*j) + (tid%j);
      int ix = i + j;
      bool up = ((i & k)==0);
      int x=key[i], y=key[ix];
      if ((x>y)==up){ key[i]=y; key[ix]=x; }
      __syncthreads();
    }
  }
  if (tid==0){
    int* svl=a.iws+ISVL+b*400; int* gvv=a.iws+IGV+b*400;
    int* gls=a.iws+IGLS+b*401;
    int ng=0, prev=-1;
    for (int i=0;i<400;i++){
      int kk=key[i]; int tok=kk/400, l=kk-tok*400;
      svl[i]=l;
      if (tok!=prev){ gvv[ng]=tok; gls[ng]=i; ng++; prev=tok; }
    }
    gls[ng]=400;
    a.iws[INGR+b]=ng;
    key[512]=ng;
  }
  __syncthreads();
  int ng=key[512];
  const int* gvv=a.iws+IGV+b*400;
  for (int c=tid;c<=256;c+=NT){
    int target=(c<256)? chunkStart(c) : 0x7FFFFFFF;
    int lo=0,hi=ng;
    while(lo<hi){ int mid=(lo+hi)>>1; if (gvv[mid]<target) lo=mid+1; else hi=mid; }
    a.iws[ICG0+b*257+c]=lo;
  }
}

// ---- LDS-tiled GEMM: MODE 0: gi = X[6400][100] @ {Wfih;Wbih}^T (cols 900, +bias)
//                      MODE 1: MNQ = ENC[6400][300] @ Wcat2^T (cols 301)
template<int MODE>
__device__ void tileGemm(const Args& a, char* smem){
  float* Xl=(float*)smem;            // [64][100] f
  float* Wl=(float*)(smem+25600);    // [64][100] f
  const int K   = MODE? 300 : 100;
  const int NC  = MODE? 301 : 900;
  const int nCT = MODE? 5 : 15;
  const int nTiles = 100*nCT;
  const float* X = a.out + (MODE? SO_ENC : SO_EMB);
  int ty=threadIdx.x>>4, tx=threadIdx.x&15;
  for (int tile=blockIdx.x; tile<nTiles; tile+=NB){
    int rt=tile%100, ct=tile/100;
    int r0=rt*64, c0=ct*64;
    float acc[4][4];
    #pragma unroll
    for (int i=0;i<4;i++){
      #pragma unroll
      for (int j=0;j<4;j++) acc[i][j]=0.f;
    }
    for (int k0=0;k0<K;k0+=100){
      for (int i=threadIdx.x;i<1600;i+=NT){
        int rr=i/25, e4=i%25;
        ((float4*)Xl)[rr*25+e4] = *((const float4*)(X + (long)(r0+rr)*K + k0) + e4);
      }
      for (int i=threadIdx.x;i<1600;i+=NT){
        int rr=i/25, e4=i%25; int c=c0+rr;
        float4 w={0.f,0.f,0.f,0.f};
        if (c<NC){
          const float* wr;
          if (MODE==0) wr = (c<450)? (a.Wfih + (long)c*100) : (a.Wbih + (long)(c-450)*100);
          else         wr = a.out + SO_WCAT + (long)c*300 + k0;
          w = *((const float4*)wr + e4);
        }
        ((float4*)Wl)[rr*25+e4]=w;
      }
      __syncthreads();
      for (int k4=0;k4<25;k4++){
        float4 a4[4], b4[4];
        #pragma unroll
        for (int i=0;i<4;i++) a4[i]=((float4*)Xl)[(ty*4+i)*25+k4];
        #pragma unroll
        for (int j=0;j<4;j++) b4[j]=((float4*)Wl)[(tx*4+j)*25+k4];
        #pragma unroll
        for (int i=0;i<4;i++){
          #pragma unroll
          for (int j=0;j<4;j++){
            acc[i][j] += a4[i].x*b4[j].x;
            acc[i][j] += a4[i].y*b4[j].y;
            acc[i][j] += a4[i].z*b4[j].z;
            acc[i][j] += a4[i].w*b4[j].w;
          }
        }
      }
      __syncthreads();
    }
    #pragma unroll
    for (int i=0;i<4;i++){
      #pragma unroll
      for (int j=0;j<4;j++){
        int r=r0+ty*4+i, c=c0+tx*4+j;
        if (c<NC){
          if (MODE==0){
            int dir=c/450, cc=c-dir*450;
            float v=acc[i][j] + (dir? a.bbih : a.bfih)[cc];
            a.out[(dir?SO_GIB:SO_GIF) + (long)r*450 + cc]=v;
          } else {
            if (c<200)      a.ws[OFF_M + (long)r*200 + c]=acc[i][j];
            else if (c<300) a.ws[OFF_N + (long)r*100 + (c-200)]=acc[i][j];
            else            a.ws[OFF_Q + r]=acc[i][j];
          }
        }
      }
    }
  }
}

// ---- encoder: 8 blocks per direction, 400 steps, 8-wide sub-barrier ----
__device__ void encoderPhase(const Args& a, int bid, char* smem, int* bar, int* abrt){
  int tid=threadIdx.x;
  int dir=bid>>3, sub=bid&7;
  int J0=sub*19; int JN = (150-J0 < 19)? (150-J0) : 19;
  int* ecnt=bar+64+dir*64; int* egen=ecnt+32;
  float* hp=(float*)smem;  // [16][150]
  const float* Whh=dir? a.Wbhh : a.Wfhh;
  const float* bhh=dir? a.bbhh : a.bfhh;
  for (int s=0;s<400;s++){
    int l=dir? 399-s : s;
    int rp=(s&1)^1, wp=s&1;
    const float* hsrc=a.ws+OFF_HENC+(long)(dir*2+rp)*2400;
    float*       hdst=a.ws+OFF_HENC+(long)(dir*2+wp)*2400;
    for (int i=tid;i<2400;i+=NT) hp[i]=hsrc[i];
    __syncthreads();
    const float* giB=a.out+(dir?SO_GIB:SO_GIF)+(long)l*16*450;
    for (int u=tid;u<JN*16;u+=NT){
      int j=J0+u/16, b=u&15;
      const float* h=hp+b*150;
      const float* wr=Whh+(long)j*150;
      const float* wz=Whh+(long)(150+j)*150;
      const float* wn=Whh+(long)(300+j)*150;
      float ar=0.f, az=0.f, an=0.f;
      for (int k=0;k<150;k++){ float hv=h[k]; ar+=hv*wr[k]; az+=hv*wz[k]; an+=hv*wn[k]; }
      const float* gi=giB+b*450;
      float r=sigm(gi[j]      + ar + bhh[j]);
      float z=sigm(gi[150+j]  + az + bhh[150+j]);
      float n=tanhf(gi[300+j] + r*(an + bhh[300+j]));
      float hv2=(1.f-z)*n + z*h[j];
      hdst[b*150+j]=hv2;
      a.out[SO_ENC + (long)(l*16+b)*300 + dir*150 + j]=hv2;
    }
    gbar(ecnt,egen,8,abrt);
  }
}

// ---- decoder S1: argmax(t-1) + GRU (blocks 0..49, 4 j each) ----
__device__ void s1Phase(const Args& a, int bid, int t, char* smem){
  int tid=threadIdx.x;
  int q=t&1, p1=q^1;
  unsigned long long* mred=(unsigned long long*)smem;      // [16][17]
  float* xw  =(float*)(smem+2176);                          // [16][100]
  float* hw  =(float*)(smem+8576);                          // [16][200]
  float* zred=(float*)(smem+21376);                         // [16][17]
  int* tokL  =(int*)(smem+22464);                           // [16]
  if (t==0){
    if (tid<16) tokL[tid]=SOS_TOK;
    __syncthreads();
  } else {
    int b=tid>>4, sg=tid&15;
    float zs=0.f;
    for (int c=sg;c<256;c+=16) zs+=a.ws[OFF_PSUM + c*16 + b];
    zred[b*17+sg]=zs;
    __syncthreads();
    if (tid<16){
      float z=0.f;
      for (int s2=0;s2<16;s2++) z+=zred[tid*17+s2];
      zred[tid*17+16]=z;
      if (bid==0) a.ws[OFF_ZLOG + p1*16 + tid]=z;
    }
    __syncthreads();
    {
      float Z=zred[b*17+16];
      unsigned long long best=0;
      for (int c=sg;c<256;c+=16){
        unsigned long long pm=a.pmax[c*16+b];
        float ev=__uint_as_float((unsigned)(pm>>32));
        int v=(int)(~(unsigned)(pm & 0xFFFFFFFFull));
        unsigned long long pk=packvi(ev/Z, v);
        if (pk>best) best=pk;
      }
      int ng=a.iws[INGR+b];
      const float* cd=a.ws+OFF_CAND + ((long)p1*16+b)*800;
      const int* gvv=a.iws+IGV+b*400;
      for (int g=sg;g<ng;g+=16){
        unsigned long long pk=packvi(cd[g*2]/Z + cd[g*2+1], gvv[g]);
        if (pk>best) best=pk;
      }
      mred[b*17+sg]=best;
    }
    __syncthreads();
    if (tid<16){
      unsigned long long best=0;
      for (int s2=0;s2<16;s2++) if (mred[tid*17+s2]>best) best=mred[tid*17+s2];
      tokL[tid]=(int)(~(unsigned)(best & 0xFFFFFFFFull));
    }
    __syncthreads();
  }
  for (int i=tid;i<1600;i+=NT){ int b=i/100, e=i-b*100; xw[i]=a.emb[(long)tokL[b]*100+e]; }
  for (int i=tid;i<3200;i+=NT) hw[i]=a.ws[OFF_HDEC + (long)p1*3200 + i];
  __syncthreads();
  int unit=tid>>2, lane=tid&3;
  int ju=unit>>4, b=unit&15;
  int j=bid*4+ju;
  float air=0,aiz=0,ain=0,ahr=0,ahz=0,ahn=0;
  const float* x=xw+b*100;
  for (int k=lane;k<100;k+=4){
    float xv=x[k];
    air+=xv*a.dWih[(long)j*100+k];
    aiz+=xv*a.dWih[(long)(200+j)*100+k];
    ain+=xv*a.dWih[(long)(400+j)*100+k];
  }
  const float* h=hw+b*200;
  for (int k=lane;k<200;k+=4){
    float hv=h[k];
    ahr+=hv*a.dWhh[(long)j*200+k];
    ahz+=hv*a.dWhh[(long)(200+j)*200+k];
    ahn+=hv*a.dWhh[(long)(400+j)*200+k];
  }
  for (int off=2;off;off>>=1){
    air+=__shfl_xor(air,off,4); aiz+=__shfl_xor(aiz,off,4); ain+=__shfl_xor(ain,off,4);
    ahr+=__shfl_xor(ahr,off,4); ahz+=__shfl_xor(ahz,off,4); ahn+=__shfl_xor(ahn,off,4);
  }
  if (lane==0){
    float r=sigm(air + a.dbih[j]     + ahr + a.dbhh[j]);
    float z=sigm(aiz + a.dbih[200+j] + ahz + a.dbhh[200+j]);
    float n=tanhf(ain + a.dbih[400+j] + r*(ahn + a.dbhh[400+j]));
    a.ws[OFF_HDEC + (long)q*3200 + b*200 + j] = (1.f-z)*n + z*h[j];
  }
}

// ---- decoder S2: energies + ctx partials (blocks 0..63) ; preh (64..79) ----
__device__ void s2Phase(const Args& a, int bid, int t, char* smem){
  int tid=threadIdx.x;
  int q=t&1, p1=q^1;
  if (bid<64){
    int b=bid&15, lg=bid>>4, l0=lg*100;
    float* hb =(float*)smem;        // 200
    float* exl=hb+200;              // 100
    float* zpS=exl+100;             // 1
    for (int i=tid;i<200;i+=NT) hb[i]=a.ws[OFF_HDEC + (long)q*3200 + b*200 + i];
    if (tid==0){
      float zp=0.f;
      if (t>0) for (int g2=0;g2<4;g2++) zp+=CTXPV(p1,b,g2,101);
      zpS[0]=zp;
    }
    __syncthreads();
    int unit=tid>>1, lane=tid&1;
    if (unit<100){
      int l=l0+unit;
      const float* Mr=a.ws+OFF_M + (long)(l*16+b)*200;
      float acc=0.f;
      for (int k=lane;k<200;k+=2) acc+=hb[k]*Mr[k];
      acc+=__shfl_xor(acc,1,2);
      if (lane==0){
        float* cov=a.ws+OFF_COVER + b*400 + l;
        float cv=*cov;
        if (t>0) cv += a.ws[OFF_EXPE + (long)p1*6400 + l*16 + b] / zpS[0];
        *cov=cv;
        float en = acc + a.bilb[0] + a.cw[0]*logf(cv + 1e-31f);
        float ex = expf(en);
        a.ws[OFF_EXPE + (long)q*6400 + l*16 + b]=ex;
        exl[unit]=ex;
      }
    }
    __syncthreads();
    if (tid<102){
      int k=tid; float acc=0.f;
      if (k<100){
        for (int ll=0;ll<100;ll++) acc+=exl[ll]*a.ws[OFF_N + (long)((l0+ll)*16+b)*100 + k];
      } else if (k==100){
        for (int ll=0;ll<100;ll++) acc+=exl[ll]*a.ws[OFF_Q + (l0+ll)*16 + b];
      } else {
        for (int ll=0;ll<100;ll++) acc+=exl[ll];
      }
      CTXPV(q,b,lg,k)=acc;
    }
  } else if (bid<80){
    int b=bid-64;
    float* hb=(float*)smem;
    for (int i=tid;i<200;i+=NT) hb[i]=a.ws[OFF_HDEC + (long)q*3200 + b*200 + i];
    __syncthreads();
    int unit=tid>>1, lane=tid&1;
    if (unit<101){
      const float* w=(unit<100)? (a.preW + (long)unit*500) : a.ptrW;
      float acc=0.f;
      for (int k=lane;k<200;k+=2) acc+=hb[k]*w[k];
      acc+=__shfl_xor(acc,1,2);
      if (lane==0) a.ws[OFF_PREH + ((long)q*16+b)*104 + unit]=acc;
    }
  }
}

// ---- decoder S4: writeback(t-1) + logits/exp(t) + psum/pmax/cand ----
__device__ void s4Phase(const Args& a, int bid, int t, char* smem){
  int tid=threadIdx.x;
  int q=t&1, p1=q^1;
  int c=bid, v0=chunkStart(c), nv=chunkSize(c);
  float* preL=(float*)smem;            // [16][100]
  float* exL =(float*)(smem+6400);     // [118][17]
  float* zaL =(float*)(smem+14432);    // 16
  float* ppqL=zaL+16; float* pp1L=zaL+32; float* zl1L=zaL+48;
  if (tid<16){
    int b=tid;
    float za=0.f, qc=0.f;
    for (int g2=0;g2<4;g2++){ za+=CTXPV(q,b,g2,101); qc+=CTXPV(q,b,g2,100); }
    zaL[b]=za;
    ppqL[b]=sigm(qc/za + a.ws[OFF_PREH + ((long)q*16+b)*104 + 100] + a.ptrb[0]);
    if (t>0){
      float za1=0.f, qc1=0.f;
      for (int g2=0;g2<4;g2++){ za1+=CTXPV(p1,b,g2,101); qc1+=CTXPV(p1,b,g2,100); }
      pp1L[b]=sigm(qc1/za1 + a.ws[OFF_PREH + ((long)p1*16+b)*104 + 100] + a.ptrb[0]);
      zl1L[b]=a.ws[OFF_ZLOG + p1*16 + b];
    }
  }
  __syncthreads();
  for (int u=tid;u<1600;u+=NT){
    int b=u/100, k=u-b*100;
    float s4v=0.f;
    for (int g2=0;g2<4;g2++) s4v+=CTXPV(q,b,g2,k);
    preL[u]=s4v/zaL[b] + a.ws[OFF_PREH + ((long)q*16+b)*104 + k] + a.preb[k];
  }
  __syncthreads();
  if (t>0){
    for (int b2=0;b2<16;b2++){
      float sc=(1.f-pp1L[b2])/zl1L[b2];
      float* row=a.out + ((long)(t-1)*16+b2)*30000;
      for (int vl=tid;vl<nv;vl+=NT) row[v0+vl]*=sc;
    }
    __syncthreads();
    if (tid<16){
      int b=tid;
      const int* cg0=a.iws+ICG0+b*257; const int* gvv=a.iws+IGV+b*400;
      const float* cd=a.ws+OFF_CAND + ((long)p1*16+b)*800;
      float* row=a.out + ((long)(t-1)*16+b)*30000;
      for (int g=cg0[c];g<cg0[c+1];g++)
        atomicAdd(row+gvv[g], cd[g*2+1]*(1.f-pp1L[b]));
    }
    __syncthreads();
  }
  // logits: thread owns fixed b = tid&15, pre[b] in registers
  int bloc=tid&15;
  float4 preg[25];
  {
    const float4* p4=(const float4*)(preL + bloc*100);
    #pragma unroll
    for (int e4=0;e4<25;e4++) preg[e4]=p4[e4];
  }
  int nu=nv*16;
  const float4* emb4=(const float4*)a.emb;
  for (int u=tid;u<nu;u+=NT){
    int vl=u>>4; int v=v0+vl;
    float acc=a.outb[v];
    const float4* er=emb4 + (long)v*25;
    #pragma unroll
    for (int e4=0;e4<25;e4++){
      float4 A=er[e4], Bv=preg[e4];
      acc += A.x*Bv.x + A.y*Bv.y + A.z*Bv.z + A.w*Bv.w;
    }
    exL[vl*17+bloc]=expf(acc);
  }
  __syncthreads();
  // coalesced row writes
  for (int b2=0;b2<16;b2++){
    float* row=a.out + ((long)t*16+b2)*30000;
    for (int vl=tid;vl<nv;vl+=NT) row[v0+vl]=exL[vl*17+b2];
  }
  // psum / pmax per b
  {
    int b=tid>>4, sg=tid&15;
    float s=0.f; unsigned long long m=0;
    for (int vl=sg;vl<nv;vl+=16){
      float ex=exL[vl*17+b];
      s+=ex;
      unsigned long long pk=packvi(ex, v0+vl);
      if (pk>m) m=pk;
    }
    for (int off=8;off;off>>=1){
      s+=__shfl_xor(s,off,16);
      unsigned long long om=__shfl_xor(m,off,16);
      if (om>m) m=om;
    }
    if (sg==0){ a.ws[OFF_PSUM + c*16 + b]=s; a.pmax[c*16+b]=m; }
  }
  // candidates for this chunk's scatter groups
  if (tid<16){
    int b=tid;
    const int* cg0=a.iws+ICG0+b*257; const int* gvv=a.iws+IGV+b*400;
    const int* gls=a.iws+IGLS+b*401; const int* svl=a.iws+ISVL+b*400;
    float* cd=a.ws+OFF_CAND + ((long)q*16+b)*800;
    float pfac=ppqL[b]/(1.f-ppqL[b]);
    for (int g=cg0[c];g<cg0[c+1];g++){
      int v=gvv[g];
      float gs=0.f;
      for (int i2=gls[g];i2<gls[g+1];i2++) gs+=a.ws[OFF_EXPE + (long)q*6400 + svl[i2]*16 + b];
      cd[g*2]  =exL[(v-v0)*17+b];
      cd[g*2+1]=pfac*gs/zaL[b];
    }
  }
}

// ---- final writeback of step T-1 ----
__device__ void finPhase(const Args& a, int bid, char* smem){
  int tid=threadIdx.x;
  int q=(Tt-1)&1;  // 0
  int c=bid, v0=chunkStart(c), nv=chunkSize(c);
  float* Zf=(float*)smem; float* ppf=Zf+16;
  if (tid<16){
    int b=tid; float z=0.f;
    for (int cc=0;cc<256;cc++) z+=a.ws[OFF_PSUM + cc*16 + b];
    Zf[b]=z;
    float za=0.f, qc=0.f;
    for (int g2=0;g2<4;g2++){ za+=CTXPV(q,b,g2,101); qc+=CTXPV(q,b,g2,100); }
    ppf[b]=sigm(qc/za + a.ws[OFF_PREH + ((long)q*16+b)*104 + 100] + a.ptrb[0]);
  }
  __syncthreads();
  for (int b2=0;b2<16;b2++){
    float sc=(1.f-ppf[b2])/Zf[b2];
    float* row=a.out + ((long)(Tt-1)*16+b2)*30000;
    for (int vl=tid;vl<nv;vl+=NT) row[v0+vl]*=sc;
  }
  __syncthreads();
  if (tid<16){
    int b=tid;
    const int* cg0=a.iws+ICG0+b*257; const int* gvv=a.iws+IGV+b*400;
    const float* cd=a.ws+OFF_CAND + ((long)q*16+b)*800;
    float* row=a.out + ((long)(Tt-1)*16+b)*30000;
    for (int g=cg0[c];g<cg0[c+1];g++)
      atomicAdd(row+gvv[g], cd[g*2+1]*(1.f-ppf[b]));
  }
}

__global__ void kInitBar(int* bar){
  if (threadIdx.x<192) bar[threadIdx.x]=0;
}

__global__ __launch_bounds__(NT,1) void mega(Args a){
  __shared__ __align__(16) char smem[53248];
  int bid=blockIdx.x, tid=threadIdx.x;
  int* bar=a.bar;
  int* gcnt=bar; int* ggen=bar+32; int* abrt=bar+190;

  // ---- P0a: sort (blocks 0..15) | emb gather X + zero cover/henc (16..255) ----
  if (bid<16){
    sortB(a,bid,smem);
  } else {
    for (long i=(long)(bid-16)*NT+tid; i<640000; i+=240L*NT){
      long pair=i/100; int e=(int)(i-pair*100);
      a.out[SO_EMB+i]=a.emb[(long)a.itok[pair]*100+e];
    }
    for (int i=(bid-16)*NT+tid; i<6400; i+=240*NT) a.ws[OFF_COVER+i]=0.f;
    for (int i=(bid-16)*NT+tid; i<9600; i+=240*NT) a.ws[OFF_HENC+i]=0.f;
  }
  gbar(gcnt,ggen,NB,abrt);

  // ---- P0b: gi GEMM ----
  tileGemm<0>(a,smem);
  gbar(gcnt,ggen,NB,abrt);

  // ---- P1: encoder (blocks 0..15; others park on the global barrier) ----
  if (bid<16) encoderPhase(a,bid,smem,bar,abrt);
  gbar(gcnt,ggen,NB,abrt);

  // ---- P2a: stage Wcat2 + adapter h0 ----
  for (long i=(long)bid*NT+tid; i<90300; i+=(long)NB*NT){
    int rr=(int)(i/300), k=(int)(i-(long)rr*300);
    float v;
    if (rr<200)      v=a.bilW[(long)rr*300+k];
    else if (rr<300) v=a.preW[(long)(rr-200)*500+200+k];
    else             v=a.ptrW[200+k];
    a.out[SO_WCAT+i]=v;
  }
  if (bid>=16 && bid<20){
    int u0=(bid-16)*800;
    for (int u=u0+tid; u<u0+800; u+=NT){
      int b=u/200, j=u-b*200;
      const float* w=a.adW+(long)j*300;
      const float* hf=a.ws+OFF_HENC + 1L*2400 + b*150;   // dir0 parity1
      const float* hb=a.ws+OFF_HENC + 3L*2400 + b*150;   // dir1 parity1
      float acc=a.adb[j];
      for (int e=0;e<150;e++) acc+=hf[e]*w[e];
      for (int e=0;e<150;e++) acc+=hb[e]*w[150+e];
      a.ws[OFF_HDEC + 1L*3200 + b*200 + j]=acc;          // h0 at parity 1
    }
  }
  gbar(gcnt,ggen,NB,abrt);

  // ---- P2b: M/N/Q GEMM ----
  tileGemm<1>(a,smem);
  gbar(gcnt,ggen,NB,abrt);

  // ---- P3: decoder ----
  for (int t=0;t<Tt;t++){
    if (bid<50) s1Phase(a,bid,t,smem);
    gbar(gcnt,ggen,NB,abrt);
    if (bid<80) s2Phase(a,bid,t,smem);
    gbar(gcnt,ggen,NB,abrt);
    s4Phase(a,bid,t,smem);
    gbar(gcnt,ggen,NB,abrt);
  }
  finPhase(a,bid,smem);
}

} // namespace

extern "C" void kernel_launch(void* const* d_in, const int* in_sizes, int n_in,
                              void* d_out, int out_size, void* d_ws, size_t ws_size,
                              hipStream_t stream) {
  Args a;
  a.itok=(const int*)d_in[0];
  a.emb =(const float*)d_in[1];
  a.Wfih=(const float*)d_in[2]; a.Wfhh=(const float*)d_in[3];
  a.bfih=(const float*)d_in[4]; a.bfhh=(const float*)d_in[5];
  a.Wbih=(const float*)d_in[6]; a.Wbhh=(const float*)d_in[7];
  a.bbih=(const float*)d_in[8]; a.bbhh=(const float*)d_in[9];
  a.adW =(const float*)d_in[10]; a.adb=(const float*)d_in[11];
  a.dWih=(const float*)d_in[12]; a.dWhh=(const float*)d_in[13];
  a.dbih=(const float*)d_in[14]; a.dbhh=(const float*)d_in[15];
  a.bilW=(const float*)d_in[16]; a.bilb=(const float*)d_in[17];
  a.cw  =(const float*)d_in[18];
  a.ptrW=(const float*)d_in[19]; a.ptrb=(const float*)d_in[20];
  a.preW=(const float*)d_in[21]; a.preb=(const float*)d_in[22];
  a.outb=(const float*)d_in[23];
  a.out =(float*)d_out;
  a.ws  =(float*)d_ws;
  a.pmax=(unsigned long long*)((char*)d_ws + PMAX_BYTE);
  a.iws =(int*)((char*)d_ws + IWS_BYTE);
  a.bar =(int*)((char*)d_ws + BAR_BYTE);
  // requires ws_size >= ~8.2 MB (round-1 demonstrated >= 9.47 MB available)

  kInitBar<<<dim3(1),dim3(256),0,stream>>>(a.bar);
  void* kargs[] = { (void*)&a };
  hipLaunchCooperativeKernel(reinterpret_cast<const void*>(mega),
                             dim3(NB), dim3(NT), kargs, 0, stream);
}

// Round 3
// 14294.939 us; speedup vs baseline: 1.3728x; 1.3728x over previous
//
#include <hip/hip_runtime.h>

namespace {

constexpr int Vv=30000, Ll=400, Bb=16, Tt=145;
constexpr int Ee=100, EHh=150, DHh=200, ENc=300;
constexpr int SOS_TOK=1;
constexpr int NB=256, NT=512;

// ---- d_out used as scratch before decoder writes it (time-disjoint) ----
constexpr long SO_EMB = 0;                      // [6400][100]
constexpr long SO_GIF = SO_EMB + 6400L*100;     // [6400][450]
constexpr long SO_GIB = SO_GIF + 6400L*450;     // [6400][450]
constexpr long SO_ENC = SO_GIB + 6400L*450;     // [6400][300]
constexpr long SO_WCAT= SO_GIF;                 // [301][300] staged after encoder

// ---- ws float offsets ----
constexpr long OFF_M    = 0;                    // [6400][200] plain, L2-hot
constexpr long OFF_N    = OFF_M + 6400L*200;    // [6400][100] plain
constexpr long OFF_Q    = OFF_N + 6400L*100;    // [6400] plain
constexpr long OFF_HENC = OFF_Q + 6400;         // [2dir*16][150] plain (final h only)
constexpr long OFF_HDEC = OFF_HENC + 2L*16*150; // [2par][16][200] ATOMIC domain
constexpr long OFF_COVER= OFF_HDEC + 2L*16*200; // [16][400] plain, owner-only
constexpr long OFF_EXPE = OFF_COVER + 6400;     // [2par][400][16] ATOMIC
constexpr long OFF_PREH = OFF_EXPE + 2L*6400;   // [2par][16][104] ATOMIC
constexpr long OFF_CTXP = OFF_PREH + 2L*16*104; // [2par][16][4][104] ATOMIC
constexpr long OFF_PSUM = OFF_CTXP + 2L*16*4*104; // [256][16] ATOMIC
constexpr long OFF_ZLOG = OFF_PSUM + 4096;      // [2][16] ATOMIC
constexpr long OFF_CAND = OFF_ZLOG + 32;        // [2][16][400][2] ATOMIC
constexpr long WS_F32_END = OFF_CAND + 2L*16*400*2;
constexpr long PMAX_BYTE = ((WS_F32_END*4 + 255)/256)*256;   // u64 [256][16] ATOMIC
constexpr long IWS_BYTE  = PMAX_BYTE + 4096L*8;
constexpr int ISVL=0, IGV=6400, IGLS=12800, ICG0=19216, INGR=23328; // ints, end 23344
constexpr long BAR_BYTE  = ((IWS_BYTE + 23344L*4 + 255)/256)*256;   // 512 ints
// bar int offsets
constexpr int HCNT=0, HGEN=32, LGEN=64, LROOT=96, LGRP=128, ABRT=384;

struct Args {
  const int* itok;
  const float* emb;
  const float* Wfih; const float* Wfhh; const float* bfih; const float* bfhh;
  const float* Wbih; const float* Wbhh; const float* bbih; const float* bbhh;
  const float* adW; const float* adb;
  const float* dWih; const float* dWhh; const float* dbih; const float* dbhh;
  const float* bilW; const float* bilb; const float* cw;
  const float* ptrW; const float* ptrb;
  const float* preW; const float* preb; const float* outb;
  float* out; float* ws; unsigned long long* pmax; int* iws; int* bar;
};

__device__ __forceinline__ int chunkStart(int c){ return c*117 + (c<48? c:48); }
__device__ __forceinline__ int chunkSize(int c){ return 117 + (c<48?1:0); }
__device__ __forceinline__ float sigm(float x){ return 1.f/(1.f+expf(-x)); }
__device__ __forceinline__ unsigned long long packvi(float val, int v){
  return ((unsigned long long)__float_as_uint(val)<<32) | (unsigned)(~(unsigned)v);
}
// agent-scope relaxed atomic access (cache-bypassing, coherent across XCDs)
__device__ __forceinline__ float ald(const float* p){
  return __hip_atomic_load(p, __ATOMIC_RELAXED, __HIP_MEMORY_SCOPE_AGENT); }
__device__ __forceinline__ void ast(float* p, float v){
  __hip_atomic_store(p, v, __ATOMIC_RELAXED, __HIP_MEMORY_SCOPE_AGENT); }
__device__ __forceinline__ unsigned long long aldu(const unsigned long long* p){
  return __hip_atomic_load(p, __ATOMIC_RELAXED, __HIP_MEMORY_SCOPE_AGENT); }
__device__ __forceinline__ void astu(unsigned long long* p, unsigned long long v){
  __hip_atomic_store(p, v, __ATOMIC_RELAXED, __HIP_MEMORY_SCOPE_AGENT); }
__device__ __forceinline__ int aldi(const int* p){
  return __hip_atomic_load(p, __ATOMIC_RELAXED, __HIP_MEMORY_SCOPE_AGENT); }

#define CTXP_PTR(par,b,g2,k) (a.ws + OFF_CTXP + (((long)(par)*16+(b))*4+(g2))*104 + (k))

// ---- heavy barrier: agent fences (wbl2/inv) — setup phases only ----
__device__ __forceinline__ void hbar(int* bar){
  __syncthreads();
  if (threadIdx.x==0){
    int* cnt=bar+HCNT; int* gen=bar+HGEN; int* abrt=bar+ABRT;
    if (__hip_atomic_load(abrt, __ATOMIC_RELAXED, __HIP_MEMORY_SCOPE_AGENT)==0){
      __builtin_amdgcn_fence(__ATOMIC_RELEASE, "agent");
      int g = __hip_atomic_load(gen, __ATOMIC_RELAXED, __HIP_MEMORY_SCOPE_AGENT);
      int arr = __hip_atomic_fetch_add(cnt, 1, __ATOMIC_RELAXED, __HIP_MEMORY_SCOPE_AGENT);
      if (arr == NB-1){
        __hip_atomic_store(cnt, 0, __ATOMIC_RELAXED, __HIP_MEMORY_SCOPE_AGENT);
        __hip_atomic_fetch_add(gen, 1, __ATOMIC_RELEASE, __HIP_MEMORY_SCOPE_AGENT);
      } else {
        long long t0 = clock64();
        while (__hip_atomic_load(gen, __ATOMIC_RELAXED, __HIP_MEMORY_SCOPE_AGENT) == g){
          __builtin_amdgcn_s_sleep(2);
          if (__hip_atomic_load(abrt, __ATOMIC_RELAXED, __HIP_MEMORY_SCOPE_AGENT)!=0) break;
          if (clock64() - t0 > 400000000LL){
            __hip_atomic_store(abrt, 1, __ATOMIC_RELAXED, __HIP_MEMORY_SCOPE_AGENT);
            break;
          }
        }
      }
      __builtin_amdgcn_fence(__ATOMIC_ACQUIRE, "agent");
    }
  }
  __syncthreads();
}

// ---- light barrier: fence-free, tree arrival, relaxed atomics only ----
__device__ __forceinline__ void lbar(int* bar){
  __syncthreads();
  if (threadIdx.x==0){
    if (__hip_atomic_load(bar+ABRT, __ATOMIC_RELAXED, __HIP_MEMORY_SCOPE_AGENT)==0){
      asm volatile("s_waitcnt vmcnt(0) lgkmcnt(0)" ::: "memory");
      int g=__hip_atomic_load(bar+LGEN, __ATOMIC_RELAXED, __HIP_MEMORY_SCOPE_AGENT);
      int grp=(int)(blockIdx.x & 7);
      int arr=__hip_atomic_fetch_add(bar+LGRP+grp*32, 1, __ATOMIC_RELAXED, __HIP_MEMORY_SCOPE_AGENT);
      if (arr==31){
        __hip_atomic_store(bar+LGRP+grp*32, 0, __ATOMIC_RELAXED, __HIP_MEMORY_SCOPE_AGENT);
        int r=__hip_atomic_fetch_add(bar+LROOT, 1, __ATOMIC_RELAXED, __HIP_MEMORY_SCOPE_AGENT);
        if (r==7){
          __hip_atomic_store(bar+LROOT, 0, __ATOMIC_RELAXED, __HIP_MEMORY_SCOPE_AGENT);
          __hip_atomic_fetch_add(bar+LGEN, 1, __ATOMIC_RELAXED, __HIP_MEMORY_SCOPE_AGENT);
        }
      }
      long long t0=clock64();
      while (__hip_atomic_load(bar+LGEN, __ATOMIC_RELAXED, __HIP_MEMORY_SCOPE_AGENT)==g){
        __builtin_amdgcn_s_sleep(2);
        if (__hip_atomic_load(bar+ABRT, __ATOMIC_RELAXED, __HIP_MEMORY_SCOPE_AGENT)!=0) break;
        if (clock64()-t0>400000000LL){
          __hip_atomic_store(bar+ABRT, 1, __ATOMIC_RELAXED, __HIP_MEMORY_SCOPE_AGENT);
          break;
        }
      }
    }
  }
  __syncthreads();
}

// ---- per-b bitonic sort -> scatter group structures (512 thr) ----
__device__ void sortB(const Args& a, int b, char* smem){
  int tid=threadIdx.x;
  int* key=(int*)smem;  // 512 ints
  key[tid] = (tid<Ll)? (a.itok[tid*16+b]*Ll + tid) : 0x7FFFFFFF;
  __syncthreads();
  for (int k=2;k<=512;k<<=1){
    for (int j=k>>1;j>0;j>>=1){
      int ixj = tid^j;
      if (ixj>tid){
        int x=key[tid], y=key[ixj];
        bool up = ((tid&k)==0);
        if ((x>y)==up){ key[tid]=y; key[ixj]=x; }
      }
      __syncthreads();
    }
  }
  int* ngS=(int*)(smem+2048);
  if (tid==0){
    int* svl=a.iws+ISVL+b*400; int* gvv=a.iws+IGV+b*400;
    int* gls=a.iws+IGLS+b*401;
    int ng=0, prev=-1;
    for (int i=0;i<400;i++){
      int kk=key[i]; int tok=kk/400, l=kk-tok*400;
      svl[i]=l;
      if (tok!=prev){ gvv[ng]=tok; gls[ng]=i; ng++; prev=tok; }
    }
    gls[ng]=400;
    a.iws[INGR+b]=ng;
    ngS[0]=ng;
  }
  __syncthreads();
  int ng=ngS[0];
  const int* gvv=a.iws+IGV+b*400;
  for (int c=tid;c<=256;c+=NT){
    int target=(c<256)? chunkStart(c) : 0x7FFFFFFF;
    int lo=0,hi=ng;
    while(lo<hi){ int mid=(lo+hi)>>1; if (gvv[mid]<target) lo=mid+1; else hi=mid; }
    a.iws[ICG0+b*257+c]=lo;
  }
}

// ---- LDS-tiled GEMM (512 thr): MODE 0: gi ; MODE 1: M/N/Q ----
template<int MODE>
__device__ void tileGemm(const Args& a, char* smem){
  float* Xl=(float*)smem;            // [64][100]
  float* Wl=(float*)(smem+25600);    // [64][100]
  const int K   = MODE? 300 : 100;
  const int NC  = MODE? 301 : 900;
  const int nCT = MODE? 5 : 15;
  const int nTiles = 100*nCT;
  const float* X = a.out + (MODE? SO_ENC : SO_EMB);
  int ty=threadIdx.x>>4, tx=threadIdx.x&15;   // 32 x 16
  for (int tile=blockIdx.x; tile<nTiles; tile+=NB){
    int rt=tile%100, ct=tile/100;
    int r0=rt*64, c0=ct*64;
    float acc[2][4];
    #pragma unroll
    for (int i=0;i<2;i++){
      #pragma unroll
      for (int j=0;j<4;j++) acc[i][j]=0.f;
    }
    for (int k0=0;k0<K;k0+=100){
      for (int i=threadIdx.x;i<1600;i+=NT){
        int rr=i/25, e4=i%25;
        ((float4*)Xl)[rr*25+e4] = *((const float4*)(X + (long)(r0+rr)*K + k0) + e4);
      }
      for (int i=threadIdx.x;i<1600;i+=NT){
        int rr=i/25, e4=i%25; int c=c0+rr;
        float4 w={0.f,0.f,0.f,0.f};
        if (c<NC){
          const float* wr;
          if (MODE==0) wr = (c<450)? (a.Wfih + (long)c*100) : (a.Wbih + (long)(c-450)*100);
          else         wr = a.out + SO_WCAT + (long)c*300 + k0;
          w = *((const float4*)wr + e4);
        }
        ((float4*)Wl)[rr*25+e4]=w;
      }
      __syncthreads();
      for (int k4=0;k4<25;k4++){
        float4 a4[2], b4[4];
        #pragma unroll
        for (int i=0;i<2;i++) a4[i]=((float4*)Xl)[(ty*2+i)*25+k4];
        #pragma unroll
        for (int j=0;j<4;j++) b4[j]=((float4*)Wl)[(tx*4+j)*25+k4];
        #pragma unroll
        for (int i=0;i<2;i++){
          #pragma unroll
          for (int j=0;j<4;j++){
            acc[i][j] += a4[i].x*b4[j].x;
            acc[i][j] += a4[i].y*b4[j].y;
            acc[i][j] += a4[i].z*b4[j].z;
            acc[i][j] += a4[i].w*b4[j].w;
          }
        }
      }
      __syncthreads();
    }
    #pragma unroll
    for (int i=0;i<2;i++){
      #pragma unroll
      for (int j=0;j<4;j++){
        int r=r0+ty*2+i, c=c0+tx*4+j;
        if (c<NC){
          if (MODE==0){
            int dir=c/450, cc=c-dir*450;
            float v=acc[i][j] + (dir? a.bbih : a.bfih)[cc];
            a.out[(dir?SO_GIB:SO_GIF) + (long)r*450 + cc]=v;
          } else {
            if (c<200)      a.ws[OFF_M + (long)r*200 + c]=acc[i][j];
            else if (c<300) a.ws[OFF_N + (long)r*100 + (c-200)]=acc[i][j];
            else            a.ws[OFF_Q + r]=acc[i][j];
          }
        }
      }
    }
  }
}

// ---- encoder: one block per (dir,b); h in LDS, Whh in VGPRs; NO barriers ----
__device__ void encoderPhase(const Args& a, int bid, char* smem){
  int tid=threadIdx.x;
  int dir=bid>>4, b=bid&15;
  float* hbuf=(float*)smem;           // [2][192]  (3 regions of 64 per parity)
  float* gbuf=(float*)(smem+2048);    // [2][452]
  float* pacc=(float*)(smem+8192);    // [3][3][152]
  const float* Whh = dir? a.Wbhh : a.Wfhh;
  const float* bhh = dir? a.bbhh : a.bfhh;
  const float* giBase = a.out + (dir? SO_GIB : SO_GIF);
  int ks=tid/150; int j=tid-ks*150;
  bool act = (ks<3);
  float w[3][50];
  if (act){
    #pragma unroll
    for (int g=0;g<3;g++){
      #pragma unroll
      for (int k=0;k<50;k++)
        w[g][k]=Whh[(long)(g*150+j)*150 + ks*50 + k];
    }
  }
  float b0=0,b1=0,b2=0;
  if (act && ks==0){ b0=bhh[j]; b1=bhh[150+j]; b2=bhh[300+j]; }
  for (int i=tid;i<192;i+=NT) hbuf[i]=0.f;
  {
    int l0 = dir? 399 : 0;
    for (int i=tid;i<450;i+=NT) gbuf[i]=giBase[((long)l0*16+b)*450+i];
  }
  __syncthreads();
  for (int s=0;s<400;s++){
    int p=s&1;
    int l=dir? 399-s : s;
    if (tid>=450 && s+1<400){
      int ln=dir? 399-(s+1) : s+1;
      for (int i=tid-450;i<450;i+=62) gbuf[(p^1)*452+i]=giBase[((long)ln*16+b)*450+i];
    }
    if (act){
      float ar=0.f, az=0.f, an=0.f;
      const float* hr=hbuf + p*192 + ks*64;
      #pragma unroll
      for (int k4=0;k4<12;k4++){
        float4 h4=*(const float4*)(hr + k4*4);
        ar+=h4.x*w[0][k4*4+0]; ar+=h4.y*w[0][k4*4+1]; ar+=h4.z*w[0][k4*4+2]; ar+=h4.w*w[0][k4*4+3];
        az+=h4.x*w[1][k4*4+0]; az+=h4.y*w[1][k4*4+1]; az+=h4.z*w[1][k4*4+2]; az+=h4.w*w[1][k4*4+3];
        an+=h4.x*w[2][k4*4+0]; an+=h4.y*w[2][k4*4+1]; an+=h4.z*w[2][k4*4+2]; an+=h4.w*w[2][k4*4+3];
      }
      {
        float h48=hr[48], h49=hr[49];
        ar+=h48*w[0][48]+h49*w[0][49];
        az+=h48*w[1][48]+h49*w[1][49];
        an+=h48*w[2][48]+h49*w[2][49];
      }
      pacc[(ks*3+0)*152+j]=ar;
      pacc[(ks*3+1)*152+j]=az;
      pacc[(ks*3+2)*152+j]=an;
    }
    __syncthreads();
    if (act && ks==0){
      float ar=pacc[(0*3+0)*152+j]+pacc[(1*3+0)*152+j]+pacc[(2*3+0)*152+j];
      float az=pacc[(0*3+1)*152+j]+pacc[(1*3+1)*152+j]+pacc[(2*3+1)*152+j];
      float an=pacc[(0*3+2)*152+j]+pacc[(1*3+2)*152+j]+pacc[(2*3+2)*152+j];
      const float* gi=gbuf + p*452;
      float r=sigm(gi[j]      + ar + b0);
      float z=sigm(gi[150+j]  + az + b1);
      float n=tanhf(gi[300+j] + r*(an + b2));
      int slot=(j/50)*64 + (j%50);
      float hold=hbuf[p*192+slot];
      float hv=(1.f-z)*n + z*hold;
      hbuf[(p^1)*192+slot]=hv;
      a.out[SO_ENC + ((long)l*16+b)*300 + dir*150 + j]=hv;
      if (s==399) a.ws[OFF_HENC + ((long)dir*16+b)*150 + j]=hv;
    }
    __syncthreads();
  }
}

// ---- decoder S1: argmax(t-1) -> tok; GRU -> h(t). blocks 0..24, 8 j each ----
__device__ void s1Phase(const Args& a, int bid, int t, char* smem){
  int tid=threadIdx.x;
  int q=t&1, p1=q^1;
  float* xw=(float*)smem;             // [16][100]
  float* hw=(float*)(smem+6400);      // [16][200]
  int* tokL=(int*)(smem+19200);       // [16]
  if (t==0){
    if (tid<16) tokL[tid]=SOS_TOK;
  } else {
    int b=tid>>5, ln=tid&31;
    float zs=0.f;
    for (int c=ln;c<256;c+=32) zs+=ald(&a.ws[OFF_PSUM + c*16 + b]);
    #pragma unroll
    for (int off=16;off;off>>=1) zs+=__shfl_xor(zs,off,32);
    float Z=zs;
    if (bid==0 && ln==0) ast(&a.ws[OFF_ZLOG + p1*16 + b], Z);
    unsigned long long best=0;
    for (int c=ln;c<256;c+=32){
      unsigned long long pm=aldu(&a.pmax[c*16+b]);
      float ev=__uint_as_float((unsigned)(pm>>32));
      int v=(int)(~(unsigned)(pm & 0xFFFFFFFFull));
      unsigned long long pk=packvi(ev/Z, v);
      if (pk>best) best=pk;
    }
    int ng=a.iws[INGR+b];
    const float* cd=a.ws+OFF_CAND + ((long)p1*16+b)*800;
    const int* gvv=a.iws+IGV+b*400;
    for (int g=ln;g<ng;g+=32){
      float v1=ald(&cd[g*2]), v2=ald(&cd[g*2+1]);
      unsigned long long pk=packvi(v1/Z + v2, gvv[g]);
      if (pk>best) best=pk;
    }
    #pragma unroll
    for (int off=16;off;off>>=1){
      unsigned long long o=__shfl_xor(best,off,32);
      if (o>best) best=o;
    }
    if (ln==0) tokL[b]=(int)(~(unsigned)(best & 0xFFFFFFFFull));
  }
  __syncthreads();
  for (int i=tid;i<1600;i+=NT){ int b=i/100, e=i-b*100; xw[i]=a.emb[(long)tokL[b]*100+e]; }
  for (int i=tid;i<3200;i+=NT) hw[i]=ald(&a.ws[OFF_HDEC + (long)p1*3200 + i]);
  __syncthreads();
  int unit=tid>>2, lane=tid&3;
  int uj=unit>>4, b=unit&15;
  int j=bid*8+uj;
  float air=0,aiz=0,ain=0,ahr=0,ahz=0,ahn=0;
  const float* x=xw+b*100;
  for (int k=lane;k<100;k+=4){
    float xv=x[k];
    air+=xv*a.dWih[(long)j*100+k];
    aiz+=xv*a.dWih[(long)(200+j)*100+k];
    ain+=xv*a.dWih[(long)(400+j)*100+k];
  }
  const float* h=hw+b*200;
  for (int k=lane;k<200;k+=4){
    float hv=h[k];
    ahr+=hv*a.dWhh[(long)j*200+k];
    ahz+=hv*a.dWhh[(long)(200+j)*200+k];
    ahn+=hv*a.dWhh[(long)(400+j)*200+k];
  }
  #pragma unroll
  for (int off=2;off;off>>=1){
    air+=__shfl_xor(air,off,4); aiz+=__shfl_xor(aiz,off,4); ain+=__shfl_xor(ain,off,4);
    ahr+=__shfl_xor(ahr,off,4); ahz+=__shfl_xor(ahz,off,4); ahn+=__shfl_xor(ahn,off,4);
  }
  if (lane==0){
    float r=sigm(air + a.dbih[j]     + ahr + a.dbhh[j]);
    float z=sigm(aiz + a.dbih[200+j] + ahz + a.dbhh[200+j]);
    float n=tanhf(ain + a.dbih[400+j] + r*(ahn + a.dbhh[400+j]));
    ast(&a.ws[OFF_HDEC + (long)q*3200 + b*200 + j], (1.f-z)*n + z*h[j]);
  }
}

// ---- decoder S2: energies + ctx partials (0..63); preh (64..79) ----
__device__ void s2Phase(const Args& a, int bid, int t, char* smem){
  int tid=threadIdx.x;
  int q=t&1, p1=q^1;
  if (bid<64){
    int b=bid&15, lg=bid>>4, l0=lg*100;
    float* hb =(float*)smem;          // 200
    float* exl=(float*)(smem+1024);   // 100
    float* zpS=(float*)(smem+1536);   // 1
    for (int i=tid;i<200;i+=NT) hb[i]=ald(&a.ws[OFF_HDEC + (long)q*3200 + b*200 + i]);
    if (tid==0){
      float zp=0.f;
      if (t>0){
        #pragma unroll
        for (int g2=0;g2<4;g2++) zp+=ald(CTXP_PTR(p1,b,g2,101));
      }
      zpS[0]=zp;
    }
    __syncthreads();
    int unit=tid>>2, lane=tid&3;
    if (unit<100){
      int l=l0+unit;
      const float* Mr=a.ws+OFF_M + (long)(l*16+b)*200;
      float acc=0.f;
      for (int k=lane;k<200;k+=4) acc+=hb[k]*Mr[k];
      #pragma unroll
      for (int off=2;off;off>>=1) acc+=__shfl_xor(acc,off,4);
      if (lane==0){
        float* cov=a.ws+OFF_COVER + b*400 + l;
        float cv=*cov;
        if (t>0) cv += ald(&a.ws[OFF_EXPE + (long)p1*6400 + l*16 + b]) / zpS[0];
        *cov=cv;
        float en = acc + a.bilb[0] + a.cw[0]*logf(cv + 1e-31f);
        float ex = expf(en);
        ast(&a.ws[OFF_EXPE + (long)q*6400 + l*16 + b], ex);
        exl[unit]=ex;
      }
    }
    __syncthreads();
    if (unit<102){
      int k=unit; float acc=0.f;
      if (k<100){
        for (int ll=lane;ll<100;ll+=4) acc+=exl[ll]*a.ws[OFF_N + (long)((l0+ll)*16+b)*100 + k];
      } else if (k==100){
        for (int ll=lane;ll<100;ll+=4) acc+=exl[ll]*a.ws[OFF_Q + (l0+ll)*16 + b];
      } else {
        for (int ll=lane;ll<100;ll+=4) acc+=exl[ll];
      }
      #pragma unroll
      for (int off=2;off;off>>=1) acc+=__shfl_xor(acc,off,4);
      if (lane==0) ast(CTXP_PTR(q,b,lg,k), acc);
    }
  } else if (bid<80){
    int b=bid-64;
    float* hb=(float*)smem;
    for (int i=tid;i<200;i+=NT) hb[i]=ald(&a.ws[OFF_HDEC + (long)q*3200 + b*200 + i]);
    __syncthreads();
    int unit=tid>>2, lane=tid&3;
    if (unit<101){
      const float* w=(unit<100)? (a.preW + (long)unit*500) : a.ptrW;
      float acc=0.f;
      for (int k=lane;k<200;k+=4) acc+=hb[k]*w[k];
      #pragma unroll
      for (int off=2;off;off>>=1) acc+=__shfl_xor(acc,off,4);
      if (lane==0) ast(&a.ws[OFF_PREH + ((long)q*16+b)*104 + unit], acc);
    }
  }
}

// ---- decoder S4: writeback(t-1) + logits/exp(t) + psum/pmax/cand ----
__device__ void s4Phase(const Args& a, int bid, int t, char* smem){
  int tid=threadIdx.x;
  int q=t&1, p1=q^1;
  int c=bid, v0=chunkStart(c), nv=chunkSize(c);
  float* preL=(float*)smem;            // [16][100]
  float* exL =(float*)(smem+6400);     // [118][17]
  float* zaL =(float*)(smem+14432);    // 16
  float* ppqL=zaL+16; float* pp1L=zaL+32; float* zl1L=zaL+48;
  if (tid<16){
    int b=tid;
    float za=0.f, qc=0.f;
    #pragma unroll
    for (int g2=0;g2<4;g2++){ za+=ald(CTXP_PTR(q,b,g2,101)); qc+=ald(CTXP_PTR(q,b,g2,100)); }
    zaL[b]=za;
    ppqL[b]=sigm(qc/za + ald(&a.ws[OFF_PREH + ((long)q*16+b)*104 + 100]) + a.ptrb[0]);
    if (t>0){
      float za1=0.f, qc1=0.f;
      #pragma unroll
      for (int g2=0;g2<4;g2++){ za1+=ald(CTXP_PTR(p1,b,g2,101)); qc1+=ald(CTXP_PTR(p1,b,g2,100)); }
      pp1L[b]=sigm(qc1/za1 + ald(&a.ws[OFF_PREH + ((long)p1*16+b)*104 + 100]) + a.ptrb[0]);
      zl1L[b]=ald(&a.ws[OFF_ZLOG + p1*16 + b]);
    }
  }
  __syncthreads();
  for (int u=tid;u<1600;u+=NT){
    int b=u/100, k=u-b*100;
    float sv=0.f;
    #pragma unroll
    for (int g2=0;g2<4;g2++) sv+=ald(CTXP_PTR(q,b,g2,k));
    preL[u]=sv/zaL[b] + ald(&a.ws[OFF_PREH + ((long)q*16+b)*104 + k]) + a.preb[k];
  }
  __syncthreads();
  if (t>0){
    int tot=nv*16;
    for (int u=tid;u<tot;u+=NT){
      int b2=u/nv, vl=u-b2*nv;
      float sc=(1.f-pp1L[b2])/zl1L[b2];
      a.out[((long)(t-1)*16+b2)*30000 + v0+vl]*=sc;
    }
    __syncthreads();
    if (tid<16){
      int b=tid;
      const int* cg0=a.iws+ICG0+b*257; const int* gvv=a.iws+IGV+b*400;
      const float* cd=a.ws+OFF_CAND + ((long)p1*16+b)*800;
      float* row=a.out + ((long)(t-1)*16+b)*30000;
      for (int g=cg0[c];g<cg0[c+1];g++)
        atomicAdd(row+gvv[g], ald(&cd[g*2+1])*(1.f-pp1L[b]));
    }
    __syncthreads();
  }
  // logits: thread owns fixed b = tid&15, pre[b] in 25 float4 regs
  int bloc=tid&15;
  float4 preg[25];
  {
    const float4* p4=(const float4*)(preL + bloc*100);
    #pragma unroll
    for (int e4=0;e4<25;e4++) preg[e4]=p4[e4];
  }
  int nu=nv*16;
  const float4* emb4=(const float4*)a.emb;
  for (int u=tid;u<nu;u+=NT){
    int vl=u>>4; int v=v0+vl;
    float acc=a.outb[v];
    const float4* er=emb4 + (long)v*25;
    #pragma unroll
    for (int e4=0;e4<25;e4++){
      float4 A=er[e4], Bv=preg[e4];
      acc += A.x*Bv.x + A.y*Bv.y + A.z*Bv.z + A.w*Bv.w;
    }
    exL[vl*17+bloc]=expf(acc);
  }
  __syncthreads();
  // exp row writes (plain; block-local rows)
  {
    int tot=nv*16;
    for (int u=tid;u<tot;u+=NT){
      int b2=u/nv, vl=u-b2*nv;
      a.out[((long)t*16+b2)*30000 + v0+vl]=exL[vl*17+b2];
    }
  }
  // psum / pmax per b (32 lanes per b)
  {
    int b=tid>>5, sg=tid&31;
    float s=0.f; unsigned long long m=0;
    for (int vl=sg;vl<nv;vl+=32){
      float ex=exL[vl*17+b];
      s+=ex;
      unsigned long long pk=packvi(ex, v0+vl);
      if (pk>m) m=pk;
    }
    #pragma unroll
    for (int off=16;off;off>>=1){
      s+=__shfl_xor(s,off,32);
      unsigned long long om=__shfl_xor(m,off,32);
      if (om>m) m=om;
    }
    if (sg==0){ ast(&a.ws[OFF_PSUM + c*16 + b], s); astu(&a.pmax[c*16+b], m); }
  }
  // candidate entries for this chunk's scatter groups
  if (tid<16){
    int b=tid;
    const int* cg0=a.iws+ICG0+b*257; const int* gvv=a.iws+IGV+b*400;
    const int* gls=a.iws+IGLS+b*401; const int* svl=a.iws+ISVL+b*400;
    float* cd=a.ws+OFF_CAND + ((long)q*16+b)*800;
    float pfac=ppqL[b]/(1.f-ppqL[b]);
    for (int g=cg0[c];g<cg0[c+1];g++){
      int v=gvv[g];
      float gs=0.f;
      for (int i2=gls[g];i2<gls[g+1];i2++) gs+=ald(&a.ws[OFF_EXPE + (long)q*6400 + svl[i2]*16 + b]);
      ast(&cd[g*2],   exL[(v-v0)*17+b]);
      ast(&cd[g*2+1], pfac*gs/zaL[b]);
    }
  }
}

// ---- final writeback of step T-1 ----
__device__ void finPhase(const Args& a, int bid, char* smem){
  int tid=threadIdx.x;
  int q=(Tt-1)&1;  // 0
  int c=bid, v0=chunkStart(c), nv=chunkSize(c);
  float* Zf=(float*)smem; float* ppf=Zf+16;
  if (tid<16){
    int b=tid; float z=0.f;
    for (int cc=0;cc<256;cc++) z+=ald(&a.ws[OFF_PSUM + cc*16 + b]);
    Zf[b]=z;
    float za=0.f, qc=0.f;
    #pragma unroll
    for (int g2=0;g2<4;g2++){ za+=ald(CTXP_PTR(q,b,g2,101)); qc+=ald(CTXP_PTR(q,b,g2,100)); }
    ppf[b]=sigm(qc/za + ald(&a.ws[OFF_PREH + ((long)q*16+b)*104 + 100]) + a.ptrb[0]);
  }
  __syncthreads();
  {
    int tot=nv*16;
    for (int u=tid;u<tot;u+=NT){
      int b2=u/nv, vl=u-b2*nv;
      float sc=(1.f-ppf[b2])/Zf[b2];
      a.out[((long)(Tt-1)*16+b2)*30000 + v0+vl]*=sc;
    }
  }
  __syncthreads();
  if (tid<16){
    int b=tid;
    const int* cg0=a.iws+ICG0+b*257; const int* gvv=a.iws+IGV+b*400;
    const float* cd=a.ws+OFF_CAND + ((long)q*16+b)*800;
    float* row=a.out + ((long)(Tt-1)*16+b)*30000;
    for (int g=cg0[c];g<cg0[c+1];g++)
      atomicAdd(row+gvv[g], ald(&cd[g*2+1])*(1.f-ppf[b]));
  }
}

__global__ void kInitBar(int* bar){
  int t=threadIdx.x;
  if (t<512) bar[t]=0;
}

__global__ __launch_bounds__(NT,1) void mega(Args a){
  __shared__ __align__(16) char smem[53248];
  int bid=blockIdx.x, tid=threadIdx.x;
  int* bar=a.bar;

  // ---- P0a: sort (0..15) | emb gather + zero cover (16..255) ----
  if (bid<16){
    sortB(a,bid,smem);
  } else {
    for (long i=(long)(bid-16)*NT+tid; i<640000; i+=240L*NT){
      long pair=i/100; int e=(int)(i-pair*100);
      a.out[SO_EMB+i]=a.emb[(long)a.itok[pair]*100+e];
    }
    for (int i=(bid-16)*NT+tid; i<6400; i+=240*NT) a.ws[OFF_COVER+i]=0.f;
  }
  hbar(bar);

  // ---- P0b: gi GEMM ----
  tileGemm<0>(a,smem);
  hbar(bar);

  // ---- P1: encoder (blocks 0..31; no internal barriers) ----
  if (bid<32) encoderPhase(a,bid,smem);
  hbar(bar);

  // ---- P2a: stage WCAT + adapter h0 ----
  for (long i=(long)bid*NT+tid; i<90300; i+=(long)NB*NT){
    int rr=(int)(i/300), k=(int)(i-(long)rr*300);
    float v;
    if (rr<200)      v=a.bilW[(long)rr*300+k];
    else if (rr<300) v=a.preW[(long)(rr-200)*500+200+k];
    else             v=a.ptrW[200+k];
    a.out[SO_WCAT+i]=v;
  }
  if (bid>=32 && bid<48){
    int b=bid-32;
    int unit=tid>>1, lane=tid&1;
    if (unit<200){
      int j=unit;
      const float* w=a.adW+(long)j*300 + lane*150;
      const float* hh=a.ws+OFF_HENC + ((long)lane*16+b)*150;
      float acc=0.f;
      for (int e=0;e<150;e++) acc+=hh[e]*w[e];
      acc+=__shfl_xor(acc,1,2);
      if (lane==0) a.ws[OFF_HDEC + 1L*3200 + b*200 + j]=acc + a.adb[j];
    }
  }
  hbar(bar);

  // ---- P2b: M/N/Q GEMM ----
  tileGemm<1>(a,smem);
  hbar(bar);

  // ---- P3: decoder (light barriers only) ----
  for (int t=0;t<Tt;t++){
    if (bid<25) s1Phase(a,bid,t,smem);
    lbar(bar);
    if (bid<80) s2Phase(a,bid,t,smem);
    lbar(bar);
    s4Phase(a,bid,t,smem);
    lbar(bar);
  }
  finPhase(a,bid,smem);
}

} // namespace

extern "C" void kernel_launch(void* const* d_in, const int* in_sizes, int n_in,
                              void* d_out, int out_size, void* d_ws, size_t ws_size,
                              hipStream_t stream) {
  Args a;
  a.itok=(const int*)d_in[0];
  a.emb =(const float*)d_in[1];
  a.Wfih=(const float*)d_in[2]; a.Wfhh=(const float*)d_in[3];
  a.bfih=(const float*)d_in[4]; a.bfhh=(const float*)d_in[5];
  a.Wbih=(const float*)d_in[6]; a.Wbhh=(const float*)d_in[7];
  a.bbih=(const float*)d_in[8]; a.bbhh=(const float*)d_in[9];
  a.adW =(const float*)d_in[10]; a.adb=(const float*)d_in[11];
  a.dWih=(const float*)d_in[12]; a.dWhh=(const float*)d_in[13];
  a.dbih=(const float*)d_in[14]; a.dbhh=(const float*)d_in[15];
  a.bilW=(const float*)d_in[16]; a.bilb=(const float*)d_in[17];
  a.cw  =(const float*)d_in[18];
  a.ptrW=(const float*)d_in[19]; a.ptrb=(const float*)d_in[20];
  a.preW=(const float*)d_in[21]; a.preb=(const float*)d_in[22];
  a.outb=(const float*)d_in[23];
  a.out =(float*)d_out;
  a.ws  =(float*)d_ws;
  a.pmax=(unsigned long long*)((char*)d_ws + PMAX_BYTE);
  a.iws =(int*)((char*)d_ws + IWS_BYTE);
  a.bar =(int*)((char*)d_ws + BAR_BYTE);
  // total ws usage ~8.15 MB (round-2 demonstrated >= 8.2 MB available)

  kInitBar<<<dim3(1),dim3(512),0,stream>>>(a.bar);
  void* kargs[] = { (void*)&a };
  hipLaunchCooperativeKernel(reinterpret_cast<const void*>(mega),
                             dim3(NB), dim3(NT), kargs, 0, stream);
}

// Round 4
// 11364.536 us; speedup vs baseline: 1.7268x; 1.2579x over previous
//
#include <hip/hip_runtime.h>

namespace {

constexpr int Vv=30000, Ll=400, Bb=16, Tt=145;
constexpr int Ee=100, EHh=150, DHh=200, ENc=300;
constexpr int SOS_TOK=1;
constexpr int NB=256, NT=512;

// ---- d_out used as scratch before decoder writes it (time-disjoint) ----
constexpr long SO_EMB = 0;                      // [6400][100]
constexpr long SO_GIF = SO_EMB + 6400L*100;     // [6400][450]
constexpr long SO_GIB = SO_GIF + 6400L*450;     // [6400][450]
constexpr long SO_ENC = SO_GIB + 6400L*450;     // [6400][300]
constexpr long SO_WCAT= SO_GIF;                 // [301][300] staged after encoder

// ---- ws float offsets ----
constexpr long OFF_M    = 0;                    // [6400][200] plain, L2-hot
constexpr long OFF_N    = OFF_M + 6400L*200;    // [6400][100] plain
constexpr long OFF_Q    = OFF_N + 6400L*100;    // [6400] plain
constexpr long OFF_HENC = OFF_Q + 6400;         // [2dir*16][150] plain
constexpr long OFF_HDEC = OFF_HENC + 2L*16*150; // [2par][16][200] ATOMIC
constexpr long OFF_COVER= OFF_HDEC + 2L*16*200; // [16][400] plain, owner-only
constexpr long OFF_EXPE = OFF_COVER + 6400;     // [2par][400][16] ATOMIC
constexpr long OFF_CTXP = OFF_EXPE + 2L*6400;   // [2par][16][8][104] ATOMIC
constexpr long OFF_PRE  = OFF_CTXP + 2L*16*8*104; // [2par][16][100] ATOMIC
constexpr long OFF_PPTR = OFF_PRE + 2L*16*100;  // [2][16] ATOMIC
constexpr long OFF_ZATT = OFF_PPTR + 32;        // [2][16] ATOMIC
constexpr long OFF_PSUM = OFF_ZATT + 32;        // [2][256][16] ATOMIC
constexpr long OFF_CAND = OFF_PSUM + 2L*4096;   // [2][16][400][2] ATOMIC
constexpr long WS_F32_END = OFF_CAND + 2L*16*400*2;
constexpr long PMAX_BYTE = ((WS_F32_END*4 + 255)/256)*256;   // u64 [2][256][16]
constexpr long IWS_BYTE  = PMAX_BYTE + 2L*4096*8;
constexpr int ISVL=0, IGV=6400, IGLS=12800, ICG0=19216, INGR=23328; // ints end 23344
constexpr long BAR_BYTE  = ((IWS_BYTE + 23344L*4 + 255)/256)*256;   // 256 ints
// bar int offsets (256B-separated lines)
constexpr int HB_CNT=0, HB_GEN=32, EP_H=64, EP_CTX=96, EP_PRE=128, EP_S4=160, ABRT=192;

struct Args {
  const int* itok;
  const float* emb;
  const float* Wfih; const float* Wfhh; const float* bfih; const float* bfhh;
  const float* Wbih; const float* Wbhh; const float* bbih; const float* bbhh;
  const float* adW; const float* adb;
  const float* dWih; const float* dWhh; const float* dbih; const float* dbhh;
  const float* bilW; const float* bilb; const float* cw;
  const float* ptrW; const float* ptrb;
  const float* preW; const float* preb; const float* outb;
  float* out; float* ws; unsigned long long* pmax; int* iws; int* bar;
};

__device__ __forceinline__ int chunkStart(int c){ return c*117 + (c<48? c:48); }
__device__ __forceinline__ int chunkSize(int c){ return 117 + (c<48?1:0); }
__device__ __forceinline__ float sigm(float x){ return 1.f/(1.f+expf(-x)); }
__device__ __forceinline__ unsigned long long packvi(float val, int v){
  return ((unsigned long long)__float_as_uint(val)<<32) | (unsigned)(~(unsigned)v);
}
__device__ __forceinline__ float ald(const float* p){
  return __hip_atomic_load(p, __ATOMIC_RELAXED, __HIP_MEMORY_SCOPE_AGENT); }
__device__ __forceinline__ void ast(float* p, float v){
  __hip_atomic_store(p, v, __ATOMIC_RELAXED, __HIP_MEMORY_SCOPE_AGENT); }
__device__ __forceinline__ unsigned long long aldu(const unsigned long long* p){
  return __hip_atomic_load(p, __ATOMIC_RELAXED, __HIP_MEMORY_SCOPE_AGENT); }
__device__ __forceinline__ void astu(unsigned long long* p, unsigned long long v){
  __hip_atomic_store(p, v, __ATOMIC_RELAXED, __HIP_MEMORY_SCOPE_AGENT); }
__device__ __forceinline__ int aldi(const int* p){
  return __hip_atomic_load(p, __ATOMIC_RELAXED, __HIP_MEMORY_SCOPE_AGENT); }

#define CTXP_PTR(par,b,g2,k) (a.ws + OFF_CTXP + (((long)(par)*16+(b))*8+(g2))*104 + (k))

// ---- heavy barrier with agent fences: setup phases only ----
__device__ __forceinline__ void hbar(int* bar){
  __syncthreads();
  if (threadIdx.x==0){
    int* cnt=bar+HB_CNT; int* gen=bar+HB_GEN; int* abrt=bar+ABRT;
    if (aldi(abrt)==0){
      __builtin_amdgcn_fence(__ATOMIC_RELEASE, "agent");
      int g = aldi(gen);
      int arr = __hip_atomic_fetch_add(cnt, 1, __ATOMIC_RELAXED, __HIP_MEMORY_SCOPE_AGENT);
      if (arr == NB-1){
        __hip_atomic_store(cnt, 0, __ATOMIC_RELAXED, __HIP_MEMORY_SCOPE_AGENT);
        __hip_atomic_fetch_add(gen, 1, __ATOMIC_RELEASE, __HIP_MEMORY_SCOPE_AGENT);
      } else {
        long it=0;
        while (aldi(gen) == g){
          __builtin_amdgcn_s_sleep(2);
          if (++it > 3000000L){ __hip_atomic_store(abrt,1,__ATOMIC_RELAXED,__HIP_MEMORY_SCOPE_AGENT); break; }
          if ((it&1023)==0 && aldi(abrt)!=0) break;
        }
      }
      __builtin_amdgcn_fence(__ATOMIC_ACQUIRE, "agent");
    }
  }
  __syncthreads();
}

// ---- epoch flag sync: monotone counters, no fences ----
__device__ __forceinline__ void waitEp(int* ep, int target, int* abrt){
  if (threadIdx.x==0){
    if (aldi(abrt)==0){
      long it=0;
      while (aldi(ep) < target){
        __builtin_amdgcn_s_sleep(1);
        if (++it > 3000000L){ __hip_atomic_store(abrt,1,__ATOMIC_RELAXED,__HIP_MEMORY_SCOPE_AGENT); break; }
        if ((it&2047)==0 && aldi(abrt)!=0) break;
      }
    }
  }
  __syncthreads();
}
__device__ __forceinline__ void bumpEp(int* ep){
  __syncthreads();   // compiler drains each wave's vmcnt at the barrier
  if (threadIdx.x==0){
    asm volatile("s_waitcnt vmcnt(0) lgkmcnt(0)" ::: "memory");
    __hip_atomic_fetch_add(ep, 1, __ATOMIC_RELAXED, __HIP_MEMORY_SCOPE_AGENT);
  }
}

// ---- per-b bitonic sort -> scatter group structures ----
__device__ void sortB(const Args& a, int b, char* smem){
  int tid=threadIdx.x;
  int* key=(int*)smem;
  key[tid] = (tid<Ll)? (a.itok[tid*16+b]*Ll + tid) : 0x7FFFFFFF;
  __syncthreads();
  for (int k=2;k<=512;k<<=1){
    for (int j=k>>1;j>0;j>>=1){
      int ixj = tid^j;
      if (ixj>tid){
        int x=key[tid], y=key[ixj];
        bool up = ((tid&k)==0);
        if ((x>y)==up){ key[tid]=y; key[ixj]=x; }
      }
      __syncthreads();
    }
  }
  int* ngS=(int*)(smem+2048);
  if (tid==0){
    int* svl=a.iws+ISVL+b*400; int* gvv=a.iws+IGV+b*400;
    int* gls=a.iws+IGLS+b*401;
    int ng=0, prev=-1;
    for (int i=0;i<400;i++){
      int kk=key[i]; int tok=kk/400, l=kk-tok*400;
      svl[i]=l;
      if (tok!=prev){ gvv[ng]=tok; gls[ng]=i; ng++; prev=tok; }
    }
    gls[ng]=400;
    a.iws[INGR+b]=ng;
    ngS[0]=ng;
  }
  __syncthreads();
  int ng=ngS[0];
  const int* gvv=a.iws+IGV+b*400;
  for (int c=tid;c<=256;c+=NT){
    int target=(c<256)? chunkStart(c) : 0x7FFFFFFF;
    int lo=0,hi=ng;
    while(lo<hi){ int mid=(lo+hi)>>1; if (gvv[mid]<target) lo=mid+1; else hi=mid; }
    a.iws[ICG0+b*257+c]=lo;
  }
}

// ---- LDS-tiled GEMM: MODE 0: gi ; MODE 1: M/N/Q ----
template<int MODE>
__device__ void tileGemm(const Args& a, char* smem){
  float* Xl=(float*)smem;            // [64][100]
  float* Wl=(float*)(smem+25600);    // [64][100]
  const int K   = MODE? 300 : 100;
  const int NC  = MODE? 301 : 900;
  const int nCT = MODE? 5 : 15;
  const int nTiles = 100*nCT;
  const float* X = a.out + (MODE? SO_ENC : SO_EMB);
  int ty=threadIdx.x>>4, tx=threadIdx.x&15;
  for (int tile=blockIdx.x; tile<nTiles; tile+=NB){
    int rt=tile%100, ct=tile/100;
    int r0=rt*64, c0=ct*64;
    float acc[2][4];
    #pragma unroll
    for (int i=0;i<2;i++){
      #pragma unroll
      for (int j=0;j<4;j++) acc[i][j]=0.f;
    }
    for (int k0=0;k0<K;k0+=100){
      for (int i=threadIdx.x;i<1600;i+=NT){
        int rr=i/25, e4=i%25;
        ((float4*)Xl)[rr*25+e4] = *((const float4*)(X + (long)(r0+rr)*K + k0) + e4);
      }
      for (int i=threadIdx.x;i<1600;i+=NT){
        int rr=i/25, e4=i%25; int c=c0+rr;
        float4 w={0.f,0.f,0.f,0.f};
        if (c<NC){
          const float* wr;
          if (MODE==0) wr = (c<450)? (a.Wfih + (long)c*100) : (a.Wbih + (long)(c-450)*100);
          else         wr = a.out + SO_WCAT + (long)c*300 + k0;
          w = *((const float4*)wr + e4);
        }
        ((float4*)Wl)[rr*25+e4]=w;
      }
      __syncthreads();
      for (int k4=0;k4<25;k4++){
        float4 a4[2], b4[4];
        #pragma unroll
        for (int i=0;i<2;i++) a4[i]=((float4*)Xl)[(ty*2+i)*25+k4];
        #pragma unroll
        for (int j=0;j<4;j++) b4[j]=((float4*)Wl)[(tx*4+j)*25+k4];
        #pragma unroll
        for (int i=0;i<2;i++){
          #pragma unroll
          for (int j=0;j<4;j++){
            acc[i][j] += a4[i].x*b4[j].x;
            acc[i][j] += a4[i].y*b4[j].y;
            acc[i][j] += a4[i].z*b4[j].z;
            acc[i][j] += a4[i].w*b4[j].w;
          }
        }
      }
      __syncthreads();
    }
    #pragma unroll
    for (int i=0;i<2;i++){
      #pragma unroll
      for (int j=0;j<4;j++){
        int r=r0+ty*2+i, c=c0+tx*4+j;
        if (c<NC){
          if (MODE==0){
            int dir=c/450, cc=c-dir*450;
            float v=acc[i][j] + (dir? a.bbih : a.bfih)[cc];
            a.out[(dir?SO_GIB:SO_GIF) + (long)r*450 + cc]=v;
          } else {
            if (c<200)      a.ws[OFF_M + (long)r*200 + c]=acc[i][j];
            else if (c<300) a.ws[OFF_N + (long)r*100 + (c-200)]=acc[i][j];
            else            a.ws[OFF_Q + r]=acc[i][j];
          }
        }
      }
    }
  }
}

// ---- encoder: one block per (dir,b); h in LDS, Whh slice in VGPRs ----
__device__ void encoderPhase(const Args& a, int bid, char* smem){
  int tid=threadIdx.x;
  int dir=bid>>4, b=bid&15;
  float* hbuf=(float*)smem;           // [2][192]
  float* gbuf=(float*)(smem+2048);    // [2][452]
  float* pacc=(float*)(smem+8192);    // [9][152]
  const float* Whh = dir? a.Wbhh : a.Wfhh;
  const float* bhh = dir? a.bbhh : a.bfhh;
  const float* giBase = a.out + (dir? SO_GIB : SO_GIF);
  int ks=tid/150; int j=tid-ks*150;
  bool act = (ks<3);
  float w[3][50];
  if (act){
    #pragma unroll
    for (int g=0;g<3;g++)
      for (int k=0;k<50;k++)
        w[g][k]=Whh[(long)(g*150+j)*150 + ks*50 + k];
  }
  float b0=0,b1=0,b2=0;
  if (act && ks==0){ b0=bhh[j]; b1=bhh[150+j]; b2=bhh[300+j]; }
  for (int i=tid;i<192;i+=NT) hbuf[i]=0.f;
  {
    int l0 = dir? 399 : 0;
    for (int i=tid;i<450;i+=NT) gbuf[i]=giBase[((long)l0*16+b)*450+i];
  }
  __syncthreads();
  for (int s=0;s<400;s++){
    int p=s&1;
    int l=dir? 399-s : s;
    if (tid>=450 && s+1<400){
      int ln=dir? 399-(s+1) : s+1;
      for (int i=tid-450;i<450;i+=62) gbuf[(p^1)*452+i]=giBase[((long)ln*16+b)*450+i];
    }
    if (act){
      float ar=0.f, az=0.f, an=0.f;
      const float* hr=hbuf + p*192 + ks*64;
      #pragma unroll
      for (int k4=0;k4<12;k4++){
        float4 h4=*(const float4*)(hr + k4*4);
        ar+=h4.x*w[0][k4*4+0]; ar+=h4.y*w[0][k4*4+1]; ar+=h4.z*w[0][k4*4+2]; ar+=h4.w*w[0][k4*4+3];
        az+=h4.x*w[1][k4*4+0]; az+=h4.y*w[1][k4*4+1]; az+=h4.z*w[1][k4*4+2]; az+=h4.w*w[1][k4*4+3];
        an+=h4.x*w[2][k4*4+0]; an+=h4.y*w[2][k4*4+1]; an+=h4.z*w[2][k4*4+2]; an+=h4.w*w[2][k4*4+3];
      }
      {
        float h48=hr[48], h49=hr[49];
        ar+=h48*w[0][48]+h49*w[0][49];
        az+=h48*w[1][48]+h49*w[1][49];
        an+=h48*w[2][48]+h49*w[2][49];
      }
      pacc[(ks*3+0)*152+j]=ar;
      pacc[(ks*3+1)*152+j]=az;
      pacc[(ks*3+2)*152+j]=an;
    }
    __syncthreads();
    if (act && ks==0){
      float ar=pacc[(0*3+0)*152+j]+pacc[(1*3+0)*152+j]+pacc[(2*3+0)*152+j];
      float az=pacc[(0*3+1)*152+j]+pacc[(1*3+1)*152+j]+pacc[(2*3+1)*152+j];
      float an=pacc[(0*3+2)*152+j]+pacc[(1*3+2)*152+j]+pacc[(2*3+2)*152+j];
      const float* gi=gbuf + p*452;
      float r=sigm(gi[j]      + ar + b0);
      float z=sigm(gi[150+j]  + az + b1);
      float n=tanhf(gi[300+j] + r*(an + b2));
      int slot=(j/50)*64 + (j%50);
      float hold=hbuf[p*192+slot];
      float hv=(1.f-z)*n + z*hold;
      hbuf[(p^1)*192+slot]=hv;
      a.out[SO_ENC + ((long)l*16+b)*300 + dir*150 + j]=hv;
      if (s==399) a.ws[OFF_HENC + ((long)dir*16+b)*150 + j]=hv;
    }
    __syncthreads();
  }
}

// ---- decoder S1 (blocks 0..49): argmax(t-1) -> tok ; GRU 4 j-slices ----
__device__ void s1Phase(const Args& a, int bid, int t, char* smem){
  int tid=threadIdx.x;
  int q=t&1, p1=q^1;
  float* xw=(float*)smem;             // [16][100]
  float* hw=(float*)(smem+6400);      // [16][200]
  int* tokL=(int*)(smem+19200);       // [16]
  if (t==0){
    if (tid<16) tokL[tid]=SOS_TOK;
  } else {
    int b=tid>>5, ln=tid&31;
    float zs=0.f;
    for (int c=ln;c<256;c+=32) zs+=ald(&a.ws[OFF_PSUM + ((long)p1*256+c)*16 + b]);
    #pragma unroll
    for (int off=16;off;off>>=1) zs+=__shfl_xor(zs,off,32);
    float Z=zs;
    unsigned long long best=0;
    for (int c=ln;c<256;c+=32){
      unsigned long long pm=aldu(&a.pmax[((long)p1*256+c)*16+b]);
      float ev=__uint_as_float((unsigned)(pm>>32));
      int v=(int)(~(unsigned)(pm & 0xFFFFFFFFull));
      unsigned long long pk=packvi(ev/Z, v);
      if (pk>best) best=pk;
    }
    int ng=a.iws[INGR+b];
    const float* cd=a.ws+OFF_CAND + ((long)p1*16+b)*800;
    const int* gvv=a.iws+IGV+b*400;
    for (int g=ln;g<ng;g+=32){
      float v1=ald(&cd[g*2]), v2=ald(&cd[g*2+1]);
      unsigned long long pk=packvi(v1/Z + v2, gvv[g]);
      if (pk>best) best=pk;
    }
    #pragma unroll
    for (int off=16;off;off>>=1){
      unsigned long long o=__shfl_xor(best,off,32);
      if (o>best) best=o;
    }
    if (ln==0) tokL[b]=(int)(~(unsigned)(best & 0xFFFFFFFFull));
  }
  __syncthreads();
  for (int i=tid;i<1600;i+=NT){ int b=i/100, e=i-b*100; xw[i]=a.emb[(long)tokL[b]*100+e]; }
  for (int i=tid;i<3200;i+=NT) hw[i]=ald(&a.ws[OFF_HDEC + (long)p1*3200 + i]);
  __syncthreads();
  int pair=tid>>3, lane=tid&7;    // 64 pairs = 4 j x 16 b
  int uj=pair>>4, b=pair&15;
  int j=bid*4+uj;
  float air=0,aiz=0,ain=0,ahr=0,ahz=0,ahn=0;
  const float* x=xw+b*100;
  for (int k=lane;k<100;k+=8){
    float xv=x[k];
    air+=xv*a.dWih[(long)j*100+k];
    aiz+=xv*a.dWih[(long)(200+j)*100+k];
    ain+=xv*a.dWih[(long)(400+j)*100+k];
  }
  const float* h=hw+b*200;
  for (int k=lane;k<200;k+=8){
    float hv=h[k];
    ahr+=hv*a.dWhh[(long)j*200+k];
    ahz+=hv*a.dWhh[(long)(200+j)*200+k];
    ahn+=hv*a.dWhh[(long)(400+j)*200+k];
  }
  #pragma unroll
  for (int off=4;off;off>>=1){
    air+=__shfl_xor(air,off,8); aiz+=__shfl_xor(aiz,off,8); ain+=__shfl_xor(ain,off,8);
    ahr+=__shfl_xor(ahr,off,8); ahz+=__shfl_xor(ahz,off,8); ahn+=__shfl_xor(ahn,off,8);
  }
  if (lane==0){
    float r=sigm(air + a.dbih[j]     + ahr + a.dbhh[j]);
    float z=sigm(aiz + a.dbih[200+j] + ahz + a.dbhh[200+j]);
    float n=tanhf(ain + a.dbih[400+j] + r*(ahn + a.dbhh[400+j]));
    ast(&a.ws[OFF_HDEC + (long)q*3200 + b*200 + j], (1.f-z)*n + z*h[j]);
  }
}

// ---- decoder S2e (128 blocks): energies, cover, EXPE, ctx partials (8 groups of 50 l) ----
__device__ void s2ePhase(const Args& a, int idx, int t, char* smem){
  int tid=threadIdx.x;
  int q=t&1, p1=q^1;
  int b=idx&15, lg=idx>>4, l0=lg*50;
  float* hb =(float*)smem;          // 200
  float* exl=(float*)(smem+1024);   // 50
  float* zpS=(float*)(smem+1280);   // 1
  for (int i=tid;i<200;i+=NT) hb[i]=ald(&a.ws[OFF_HDEC + (long)q*3200 + b*200 + i]);
  if (tid==0){
    float zp=0.f;
    if (t>0){
      #pragma unroll
      for (int g2=0;g2<8;g2++) zp+=ald(CTXP_PTR(p1,b,g2,101));
    }
    zpS[0]=zp;
  }
  __syncthreads();
  int unit=tid>>3, lane=tid&7;     // 64 units, 8 lanes
  if (unit<50){
    int l=l0+unit;
    const float* Mr=a.ws+OFF_M + (long)(l*16+b)*200;
    float acc=0.f;
    for (int k=lane;k<200;k+=8) acc+=hb[k]*Mr[k];
    #pragma unroll
    for (int off=4;off;off>>=1) acc+=__shfl_xor(acc,off,8);
    if (lane==0){
      float* cov=a.ws+OFF_COVER + b*400 + l;
      float cv=*cov;
      if (t>0) cv += ald(&a.ws[OFF_EXPE + (long)p1*6400 + l*16 + b]) / zpS[0];
      *cov=cv;
      float en = acc + a.bilb[0] + a.cw[0]*logf(cv + 1e-31f);
      float ex = expf(en);
      ast(&a.ws[OFF_EXPE + (long)q*6400 + l*16 + b], ex);
      exl[unit]=ex;
    }
  }
  __syncthreads();
  int u2=tid>>2, lane2=tid&3;      // 128 units, 4 lanes
  if (u2<102){
    int k=u2; float acc=0.f;
    if (k<100){
      for (int ll=lane2;ll<50;ll+=4) acc+=exl[ll]*a.ws[OFF_N + (long)((l0+ll)*16+b)*100 + k];
    } else if (k==100){
      for (int ll=lane2;ll<50;ll+=4) acc+=exl[ll]*a.ws[OFF_Q + (l0+ll)*16 + b];
    } else {
      for (int ll=lane2;ll<50;ll+=4) acc+=exl[ll];
    }
    #pragma unroll
    for (int off=2;off;off>>=1) acc+=__shfl_xor(acc,off,4);
    if (lane2==0) ast(CTXP_PTR(q,b,lg,k), acc);
  }
}

// ---- pre-finalizer (16 blocks, one per b): PREH + reduce CTXP -> pre/pptr/zatt ----
__device__ void preFinal(const Args& a, int b, int t, char* smem, int* bar){
  int tid=threadIdx.x;
  int q=t&1;
  float* hb   =(float*)smem;          // 200
  float* prehL=(float*)(smem+1024);   // 101
  float* ctxs =(float*)(smem+1536);   // 102
  for (int i=tid;i<200;i+=NT) hb[i]=ald(&a.ws[OFF_HDEC + (long)q*3200 + b*200 + i]);
  __syncthreads();
  int unit=tid>>2, lane=tid&3;
  if (unit<101){
    const float* w=(unit<100)? (a.preW + (long)unit*500) : a.ptrW;
    float acc=0.f;
    for (int k=lane;k<200;k+=4) acc+=hb[k]*w[k];
    #pragma unroll
    for (int off=2;off;off>>=1) acc+=__shfl_xor(acc,off,4);
    if (lane==0) prehL[unit]=acc;
  }
  waitEp(bar+EP_CTX, 128*(t+1), bar+ABRT);   // includes __syncthreads
  if (tid<408){
    int k=tid>>2, lane2=tid&3;
    float acc=0.f;
    for (int g2=lane2;g2<8;g2+=4) acc+=ald(CTXP_PTR(q,b,g2,k));
    #pragma unroll
    for (int off=2;off;off>>=1) acc+=__shfl_xor(acc,off,4);
    if (lane2==0) ctxs[k]=acc;
  }
  __syncthreads();
  if (tid<100){
    int k=tid;
    ast(&a.ws[OFF_PRE + ((long)q*16+b)*100 + k], ctxs[k]/ctxs[101] + prehL[k] + a.preb[k]);
  }
  if (tid==511){
    float za=ctxs[101];
    ast(&a.ws[OFF_ZATT + (long)q*16 + b], za);
    ast(&a.ws[OFF_PPTR + (long)q*16 + b], sigm(ctxs[100]/za + prehL[100] + a.ptrb[0]));
  }
}

// ---- writeback of row tr (uses parity p1 state + LDS exPrev); nt stores, no atomics ----
__device__ void wbPhase(const Args& a, int c, int p1, int tr, float* exPrev, char* smem){
  int tid=threadIdx.x;
  int v0=chunkStart(c), nv=chunkSize(c);
  float* zpart=(float*)(smem+8192);   // [32][16]
  float* zl1=(float*)(smem+10240);    // 16
  float* pp1=(float*)(smem+10304);    // 16
  {
    int b=tid&15, seg=tid>>4;
    float z=0.f;
    for (int cc=seg;cc<256;cc+=32) z+=ald(&a.ws[OFF_PSUM + ((long)p1*256+cc)*16 + b]);
    zpart[seg*16+b]=z;
  }
  __syncthreads();
  if (tid<16){
    float z=0.f;
    for (int s2=0;s2<32;s2++) z+=zpart[s2*16+tid];
    zl1[tid]=z;
    pp1[tid]=ald(&a.ws[OFF_PPTR + (long)p1*16 + tid]);
  }
  __syncthreads();
  if (tid<16){
    int b=tid;
    float sc=(1.f-pp1[b])/zl1[b];
    const int* cg0=a.iws+ICG0+b*257; const int* gvv=a.iws+IGV+b*400;
    const float* cd=a.ws+OFF_CAND + ((long)p1*16+b)*800;
    for (int g=cg0[c];g<cg0[c+1];g++){
      int idx=(gvv[g]-v0)*17+b;
      exPrev[idx] += ald(&cd[g*2+1])*(1.f-pp1[b])/sc;
    }
  }
  __syncthreads();
  {
    int tot=nv*16;
    for (int u=tid;u<tot;u+=NT){
      int b2=u/nv, vl=u-b2*nv;
      float sc=(1.f-pp1[b2])/zl1[b2];
      __builtin_nontemporal_store(exPrev[vl*17+b2]*sc,
                                  &a.out[((long)tr*16+b2)*30000 + v0+vl]);
    }
  }
  __syncthreads();
}

// ---- decoder S4 main: pre load, logits+exp into LDS, psum/pmax/cand ----
__device__ void s4Main(const Args& a, int c, int q, float* exCur, char* smem){
  int tid=threadIdx.x;
  int v0=chunkStart(c), nv=chunkSize(c);
  float* preL=(float*)smem;           // [16][100]
  float* ppqL=(float*)(smem+6400);    // 16
  float* zaqL=(float*)(smem+6464);    // 16
  for (int u=tid;u<1600;u+=NT){
    int b=u/100, k=u-b*100;
    preL[u]=ald(&a.ws[OFF_PRE + ((long)q*16+b)*100 + k]);
  }
  if (tid<16){
    ppqL[tid]=ald(&a.ws[OFF_PPTR + (long)q*16 + tid]);
    zaqL[tid]=ald(&a.ws[OFF_ZATT + (long)q*16 + tid]);
  }
  __syncthreads();
  int bloc=tid&15;
  float4 preg[25];
  {
    const float4* p4=(const float4*)(preL + bloc*100);
    #pragma unroll
    for (int e4=0;e4<25;e4++) preg[e4]=p4[e4];
  }
  int nu=nv*16;
  const float4* emb4=(const float4*)a.emb;
  for (int u=tid;u<nu;u+=NT){
    int vl=u>>4; int v=v0+vl;
    float acc=a.outb[v];
    const float4* er=emb4 + (long)v*25;
    #pragma unroll
    for (int e4=0;e4<25;e4++){
      float4 A=er[e4], Bv=preg[e4];
      acc += A.x*Bv.x + A.y*Bv.y + A.z*Bv.z + A.w*Bv.w;
    }
    exCur[vl*17+bloc]=expf(acc);
  }
  __syncthreads();
  {
    int b=tid>>5, sg=tid&31;
    float s=0.f; unsigned long long m=0;
    for (int vl=sg;vl<nv;vl+=32){
      float ex=exCur[vl*17+b];
      s+=ex;
      unsigned long long pk=packvi(ex, v0+vl);
      if (pk>m) m=pk;
    }
    #pragma unroll
    for (int off=16;off;off>>=1){
      s+=__shfl_xor(s,off,32);
      unsigned long long om=__shfl_xor(m,off,32);
      if (om>m) m=om;
    }
    if (sg==0){
      ast(&a.ws[OFF_PSUM + ((long)q*256+c)*16 + b], s);
      astu(&a.pmax[((long)q*256+c)*16 + b], m);
    }
  }
  if (tid<16){
    int b=tid;
    const int* cg0=a.iws+ICG0+b*257; const int* gvv=a.iws+IGV+b*400;
    const int* gls=a.iws+IGLS+b*401; const int* svl=a.iws+ISVL+b*400;
    float* cd=a.ws+OFF_CAND + ((long)q*16+b)*800;
    float pfac=ppqL[b]/(1.f-ppqL[b]);
    for (int g=cg0[c];g<cg0[c+1];g++){
      int v=gvv[g];
      float gs=0.f;
      for (int i2=gls[g];i2<gls[g+1];i2++) gs+=ald(&a.ws[OFF_EXPE + (long)q*6400 + svl[i2]*16 + b]);
      ast(&cd[g*2],   exCur[(v-v0)*17+b]);
      ast(&cd[g*2+1], pfac*gs/zaqL[b]);
    }
  }
}

__global__ void kInitBar(int* bar){
  int t=threadIdx.x;
  if (t<256) bar[t]=0;
}

__global__ __launch_bounds__(NT,1) void mega(Args a){
  __shared__ __align__(16) char smem[53248];
  int bid=blockIdx.x, tid=threadIdx.x;
  int* bar=a.bar;
  int* abrt=bar+ABRT;
  float* exBuf0=(float*)(smem+36864);   // [118][17]
  float* exBuf1=(float*)(smem+44928);

  // ---- P0a: sort (0..15) | emb gather + zero cover (16..255) ----
  if (bid<16){
    sortB(a,bid,smem);
  } else {
    for (long i=(long)(bid-16)*NT+tid; i<640000; i+=240L*NT){
      long pair=i/100; int e=(int)(i-pair*100);
      a.out[SO_EMB+i]=a.emb[(long)a.itok[pair]*100+e];
    }
    for (int i=(bid-16)*NT+tid; i<6400; i+=240*NT) a.ws[OFF_COVER+i]=0.f;
  }
  hbar(bar);

  // ---- P0b: gi GEMM ----
  tileGemm<0>(a,smem);
  hbar(bar);

  // ---- P1: encoder ----
  if (bid<32) encoderPhase(a,bid,smem);
  hbar(bar);

  // ---- P2a: stage WCAT + adapter h0 ----
  for (long i=(long)bid*NT+tid; i<90300; i+=(long)NB*NT){
    int rr=(int)(i/300), k=(int)(i-(long)rr*300);
    float v;
    if (rr<200)      v=a.bilW[(long)rr*300+k];
    else if (rr<300) v=a.preW[(long)(rr-200)*500+200+k];
    else             v=a.ptrW[200+k];
    a.out[SO_WCAT+i]=v;
  }
  if (bid>=32 && bid<48){
    int b=bid-32;
    int unit=tid>>1, lane=tid&1;
    if (unit<200){
      int j=unit;
      const float* w=a.adW+(long)j*300 + lane*150;
      const float* hh=a.ws+OFF_HENC + ((long)lane*16+b)*150;
      float acc=0.f;
      for (int e=0;e<150;e++) acc+=hh[e]*w[e];
      acc+=__shfl_xor(acc,1,2);
      if (lane==0) a.ws[OFF_HDEC + 1L*3200 + b*200 + j]=acc + a.adb[j];
    }
  }
  hbar(bar);

  // ---- P2b: M/N/Q GEMM ----
  tileGemm<1>(a,smem);
  hbar(bar);

  // ---- P3: decoder, epoch-flag pipeline ----
  for (int t=0;t<Tt;t++){
    int q=t&1, p1=q^1;
    float* exPrev = p1? exBuf1 : exBuf0;
    float* exCur  = q?  exBuf1 : exBuf0;
    if (bid<50){
      waitEp(bar+EP_S4, 256*t, abrt);
      s1Phase(a,bid,t,smem);
      bumpEp(bar+EP_H);
    }
    if (t>0) wbPhase(a,bid,p1,t-1,exPrev,smem);
    if (bid>=64 && bid<192){
      waitEp(bar+EP_H, 50*(t+1), abrt);
      s2ePhase(a,bid-64,t,smem);
      bumpEp(bar+EP_CTX);
    }
    if (bid>=240){
      waitEp(bar+EP_H, 50*(t+1), abrt);
      preFinal(a,bid-240,t,smem,bar);
      bumpEp(bar+EP_PRE);
    }
    waitEp(bar+EP_PRE, 16*(t+1), abrt);
    s4Main(a,bid,q,exCur,smem);
    bumpEp(bar+EP_S4);
  }
  waitEp(bar+EP_S4, 256*Tt, abrt);
  wbPhase(a,bid,(Tt-1)&1,Tt-1,((Tt-1)&1)?exBuf1:exBuf0,smem);
}

} // namespace

extern "C" void kernel_launch(void* const* d_in, const int* in_sizes, int n_in,
                              void* d_out, int out_size, void* d_ws, size_t ws_size,
                              hipStream_t stream) {
  Args a;
  a.itok=(const int*)d_in[0];
  a.emb =(const float*)d_in[1];
  a.Wfih=(const float*)d_in[2]; a.Wfhh=(const float*)d_in[3];
  a.bfih=(const float*)d_in[4]; a.bfhh=(const float*)d_in[5];
  a.Wbih=(const float*)d_in[6]; a.Wbhh=(const float*)d_in[7];
  a.bbih=(const float*)d_in[8]; a.bbhh=(const float*)d_in[9];
  a.adW =(const float*)d_in[10]; a.adb=(const float*)d_in[11];
  a.dWih=(const float*)d_in[12]; a.dWhh=(const float*)d_in[13];
  a.dbih=(const float*)d_in[14]; a.dbhh=(const float*)d_in[15];
  a.bilW=(const float*)d_in[16]; a.bilb=(const float*)d_in[17];
  a.cw  =(const float*)d_in[18];
  a.ptrW=(const float*)d_in[19]; a.ptrb=(const float*)d_in[20];
  a.preW=(const float*)d_in[21]; a.preb=(const float*)d_in[22];
  a.outb=(const float*)d_in[23];
  a.out =(float*)d_out;
  a.ws  =(float*)d_ws;
  a.pmax=(unsigned long long*)((char*)d_ws + PMAX_BYTE);
  a.iws =(int*)((char*)d_ws + IWS_BYTE);
  a.bar =(int*)((char*)d_ws + BAR_BYTE);
  // total ws usage ~8.5 MB (round-1 demonstrated >= 9.47 MB available)

  kInitBar<<<dim3(1),dim3(256),0,stream>>>(a.bar);
  void* kargs[] = { (void*)&a };
  hipLaunchCooperativeKernel(reinterpret_cast<const void*>(mega),
                             dim3(NB), dim3(NT), kargs, 0, stream);
}